// Round 10
// baseline (1409.905 us; speedup 1.0000x reference)
//
#include <hip/hip_runtime.h>
#include <hip/hip_bf16.h>

// DeepSeek-V2 MLA prefill, B=2 S=2048 HID=2048 H=16 DN=128 DR=64 KVR=512 DV=128
// Round 10: attn = R4 structure, single-buffered K/V (77.8 KB LDS) -> 2 blocks/CU
// cross-block overlap; rescale-skip. GEMMs unchanged (R8 gload_lds template).

typedef __hip_bfloat16 bf16;
typedef __bf16 v8bf __attribute__((ext_vector_type(8)));
typedef float  v4f  __attribute__((ext_vector_type(4)));

#define S_    2048
#define SCALE_F 0.07216878364870322f   // (128+64)^-0.5

__device__ __forceinline__ void st1(float* p, float v){ *p = v; }
__device__ __forceinline__ void st1(bf16* p, float v){ *p = __float2bfloat16(v); }
__device__ __forceinline__ unsigned short bfb(float x){
  return __builtin_bit_cast(unsigned short, __float2bfloat16(x));
}
__device__ __forceinline__ unsigned pk2(float a, float b){
  return (unsigned)bfb(a) | ((unsigned)bfb(b) << 16);
}

// async global->LDS 16B (linear LDS dest = wave-uniform base + lane*16)
typedef const void __attribute__((address_space(1)))* gas_t;
typedef void __attribute__((address_space(3)))* las_t;
__device__ __forceinline__ void g2l16(const void* g, void* l){
  __builtin_amdgcn_global_load_lds((gas_t)g, (las_t)l, 16, 0, 0);
}

// ---------------- cos/sin table: (S,32) each ----------------
__global__ void cossin_kernel(const int* __restrict__ pos, float* __restrict__ cosT,
                              float* __restrict__ sinT){
  int idx = blockIdx.x*256 + threadIdx.x;       // S*32 = 65536
  int i = idx & 31, s = idx >> 5;
  float t = (float)pos[s];
  float freq = t * powf(10000.0f, -(float)i/32.0f);
  cosT[idx] = cosf(freq);
  sinT[idx] = sinf(freq);
}

// ---------------- f32 -> bf16 cast (vector x8) ------------------------------
__global__ void castf2b_kernel(const float* __restrict__ src, bf16* __restrict__ dst, int n8){
  int i = blockIdx.x*256 + threadIdx.x;
  if (i >= n8) return;
  const float4* s = (const float4*)src;
  float4 a = s[2*i], b = s[2*i+1];
  uint4 o; o.x = pk2(a.x,a.y); o.y = pk2(a.z,a.w); o.z = pk2(b.x,b.y); o.w = pk2(b.z,b.w);
  ((uint4*)dst)[i] = o;
}

// ---------------- MFMA GEMM (m97-style): C = A @ W^T ------------------------
// 128x128 tile, BK=32, dbuf LDS via global_load_lds(16B). A,W bf16 row-major.
template<typename TC>
__global__ __launch_bounds__(256) void gemm2_kernel(
    const bf16* __restrict__ A, int lda, int aDiv, long aS1, long aS2,
    const bf16* __restrict__ W, int ldw, int wDiv, long wS1, long wS2,
    TC* __restrict__ C, int ldc, int cDiv, long cS1, long cS2,
    int N, int K, float alpha)
{
  int z = blockIdx.z;
  A += (long)(z/aDiv)*aS1 + (long)(z%aDiv)*aS2;
  W += (long)(z/wDiv)*wS1 + (long)(z%wDiv)*wS2;
  C += (long)(z/cDiv)*cS1 + (long)(z%cDiv)*cS2;
  __shared__ bf16 As[2][4096];
  __shared__ bf16 Ws[2][4096];
  const int tid = threadIdx.x;
  const int w = tid>>6, l = tid&63, g = l>>4, c16 = l&15;
  const int wr = (w>>1)*64, wc = (w&1)*64;
  const int row0 = blockIdx.y*128, col0 = blockIdx.x*128;

  const long aO1 = (long)(row0 + (tid>>2))*lda + (tid&3)*8;
  const long aO2 = (long)(row0 + 64 + (tid>>2))*lda + (tid&3)*8;
  int wr1 = col0 + (tid>>2);      if (wr1 > N-1) wr1 = N-1;
  int wr2 = col0 + 64 + (tid>>2); if (wr2 > N-1) wr2 = N-1;
  const long wO1 = (long)wr1*ldw + (tid&3)*8;
  const long wO2 = (long)wr2*ldw + (tid&3)*8;

  v4f acc[4][4];
  #pragma unroll
  for (int i=0;i<4;i++)
    #pragma unroll
    for (int j=0;j<4;j++) acc[i][j] = (v4f){0.f,0.f,0.f,0.f};

  auto STAGE = [&](int k0, int bsel){
    g2l16(A + aO1 + k0, &As[bsel][tid*8]);
    g2l16(A + aO2 + k0, &As[bsel][2048 + tid*8]);
    g2l16(W + wO1 + k0, &Ws[bsel][tid*8]);
    g2l16(W + wO2 + k0, &Ws[bsel][2048 + tid*8]);
  };
  STAGE(0, 0);
  __syncthreads();
  const int nk = K >> 5;
  for (int t=0; t<nk; ++t){
    const int cur = t & 1;
    if (t+1 < nk) STAGE((t+1)*32, cur^1);
    v8bf af[4], bw[4];
    #pragma unroll
    for (int mi=0;mi<4;mi++) af[mi] = *(const v8bf*)&As[cur][(wr+mi*16+c16)*32 + g*8];
    #pragma unroll
    for (int ni=0;ni<4;ni++) bw[ni] = *(const v8bf*)&Ws[cur][(wc+ni*16+c16)*32 + g*8];
    #pragma unroll
    for (int mi=0;mi<4;mi++)
      #pragma unroll
      for (int ni=0;ni<4;ni++)
        acc[mi][ni] = __builtin_amdgcn_mfma_f32_16x16x32_bf16(af[mi], bw[ni], acc[mi][ni], 0,0,0);
    __syncthreads();
  }
  #pragma unroll
  for (int mi=0;mi<4;mi++)
    #pragma unroll
    for (int ni=0;ni<4;ni++)
      #pragma unroll
      for (int r=0;r<4;r++){
        int row = row0 + wr + mi*16 + g*4 + r;
        int col = col0 + wc + ni*16 + c16;
        if (col < N) st1(C + (long)row*ldc + col, acc[mi][ni][r]*alpha);
      }
}

// ---------------- k_b cast+transpose: (16,128,512)f32 -> (16,512,128)bf16 ----
__global__ __launch_bounds__(256) void kbT_kernel(const float* __restrict__ kb,
                                                  bf16* __restrict__ kbT){
  __shared__ bf16 t[64][65];
  int h = blockIdx.z, c0 = blockIdx.x*64, d0 = blockIdx.y*64;
  const float* src = kb + ((long)h*128 + d0)*512 + c0;
  #pragma unroll
  for (int i=0;i<16;i++){
    int idx = i*256 + threadIdx.x;
    int dl = idx>>6, cl = idx&63;
    t[dl][cl] = __float2bfloat16(src[(long)dl*512 + cl]);
  }
  __syncthreads();
  bf16* dst = kbT + ((long)h*512 + c0)*128 + d0;
  #pragma unroll
  for (int i=0;i<16;i++){
    int idx = i*256 + threadIdx.x;
    int cl = idx>>6, dl = idx&63;
    dst[(long)cl*128 + dl] = t[dl][cl];
  }
}

// ---------------- V transpose: Kb(B,S,576)[:,:512] -> Kd(B,512,S) bf16 ------
__global__ __launch_bounds__(256) void tposeV_kernel(const bf16* __restrict__ Kb,
                                                     bf16* __restrict__ Kd){
  __shared__ bf16 t[64][65];
  int b = blockIdx.z, s0 = blockIdx.y*64, d0 = blockIdx.x*64;
  const bf16* src = Kb + ((long)(b*S_ + s0))*576 + d0;
  #pragma unroll
  for (int i=0;i<16;i++){
    int idx = i*256 + threadIdx.x;
    int sl = idx>>6, dl = idx&63;
    t[sl][dl] = src[(long)sl*576 + dl];
  }
  __syncthreads();
  bf16* dst = Kd + ((long)(b*512 + d0))*S_ + s0;
  #pragma unroll
  for (int i=0;i<16;i++){
    int idx = i*256 + threadIdx.x;
    int dl = idx>>6, sl = idx&63;
    dst[(long)dl*S_ + sl] = t[sl][dl];
  }
}

// ---------------- RMSNorm(ckv) + RoPE(k_pe) -> K bf16 (B,S,576) -------------
__global__ __launch_bounds__(256) void build_k_kernel(
    const bf16* __restrict__ ckv_kpe, const float* __restrict__ ln_w,
    const float* __restrict__ cosT, const float* __restrict__ sinT,
    bf16* __restrict__ Kb)
{
  int row = blockIdx.x;            // b*S + s
  int s = row & (S_-1);
  int tid = threadIdx.x;
  const bf16* src = ckv_kpe + (long)row*576;
  float x0 = __bfloat162float(src[tid*2]), x1 = __bfloat162float(src[tid*2+1]);
  float ss = x0*x0 + x1*x1;
  #pragma unroll
  for (int o=32;o>=1;o>>=1) ss += __shfl_xor(ss, o, 64);
  __shared__ float wss[4];
  int wid = tid>>6, lane = tid&63;
  if (lane==0) wss[wid] = ss;
  __syncthreads();
  float tot = wss[0]+wss[1]+wss[2]+wss[3];
  float rs = rsqrtf(tot*(1.0f/512.0f) + 1e-6f);
  bf16* dst = Kb + (long)row*576;
  dst[tid*2]   = __float2bfloat16(x0*rs*ln_w[tid*2]);
  dst[tid*2+1] = __float2bfloat16(x1*rs*ln_w[tid*2+1]);
  if (tid < 32) {
    float p0 = __bfloat162float(src[512 + tid*2]);
    float p1 = __bfloat162float(src[512 + tid*2 + 1]);
    float c = cosT[s*32+tid], sn = sinT[s*32+tid];
    dst[512+tid] = __float2bfloat16(p0*c - p1*sn);
    dst[544+tid] = __float2bfloat16(p1*c + p0*sn);
  }
}

// ---------------- RoPE(q_pe)*SCALE -> Q cols 512..575 -----------------------
__global__ void rope_q_kernel(const bf16* __restrict__ qpe,
                              const float* __restrict__ cosT, const float* __restrict__ sinT,
                              bf16* __restrict__ Qb)
{
  int idx = blockIdx.x*256 + threadIdx.x;   // B*H*S*32 = 2097152
  int i = idx & 31;
  int s = (idx >> 5) & (S_-1);
  int z = idx >> 16;                        // b*16+n
  int b = z >> 4, n = z & 15;
  long base = ((long)(b*S_+s))*1024 + n*64 + 2*i;
  float x0 = __bfloat162float(qpe[base]), x1 = __bfloat162float(qpe[base+1]);
  float c = cosT[s*32+i], sn = sinT[s*32+i];
  bf16* dst = Qb + ((long)z*S_ + s)*576;
  dst[512+i] = __float2bfloat16((x0*c - x1*sn)*SCALE_F);
  dst[544+i] = __float2bfloat16((x1*c + x0*sn)*SCALE_F);
}

// ---------------- MFMA flash attention (round 10) ----------------------------
// R4 structure, single-buffered K/V: LDS 77824 B -> 2 blocks/CU.
// Q (B*H,S,576) bf16 pre-scaled; K (B,S,576) bf16; Kd (B,512,S) bf16 (V^T).
// 512 thr = 8 waves: 4 row-blocks x 2 d-halves. KVBLK=32, QBLK=64.
#define K_OFF  0          // 36864
#define V_OFF  36864      // 32768
#define P_OFF  69632      // 8192
#define SMEM_BYTES 77824

__global__ __launch_bounds__(512, 4) void attn_mfma_kernel(
    const bf16* __restrict__ Qg, const bf16* __restrict__ Kg,
    const bf16* __restrict__ Vdg, bf16* __restrict__ Og)
{
  extern __shared__ char smem[];
  char* kB = smem + K_OFF;
  char* vB = smem + V_OFF;
  const int tid = threadIdx.x;
  const int w   = tid >> 6;
  const int l   = tid & 63;
  const int g   = l >> 4;
  const int c16 = l & 15;
  const int R   = (w & 3) * 16;     // row block within Q tile
  const int Dh  = (w >> 2) * 256;   // O d half
  char* Pw = smem + P_OFF + w*1024; // wave-private P: 16 rows x 64B (striped swz)

  // XCD-aware mapping: each XCD works on one batch b
  const int lin = blockIdx.x;       // 0..511
  const int k8 = lin & 7;
  const int b  = k8 >> 2;
  const int u  = (lin >> 3)*4 + (k8 & 3);   // 0..255
  const int n  = u & 15;
  const int pr = u >> 4;                    // 0..15 (q-tile pair id)
  const int z  = b*16 + n;

  const char* kb0 = (const char*)Kg  + (long)b*S_*1152;
  const char* vd0 = (const char*)Vdg + (long)b*512*S_*2;

  // stage one 32-row K tile + V tile into LDS (linear dest, pre-swizzled src)
  auto STAGE = [&](int tt){
    const char* ksrc = kb0 + (long)tt*32*1152;
    #pragma unroll
    for (int it=0; it<4; it++){
      int c = it*512 + tid;                 // 2304 chunks total
      int kcol = c/72, j = c - kcol*72;
      g2l16(ksrc + kcol*1152 + ((j ^ (kcol&7))<<4), kB + c*16);
    }
    if (tid < 256){
      int c = 2048 + tid;
      int kcol = c/72, j = c - kcol*72;
      g2l16(ksrc + kcol*1152 + ((j ^ (kcol&7))<<4), kB + c*16);
    }
    const char* vsrc = vd0 + (long)tt*64;   // kt0*2 bytes
    #pragma unroll
    for (int it=0; it<4; it++){
      int c = it*512 + tid;                 // 2048 chunks
      int s = c>>3, uu = (c&7) ^ (s&7);
      int d = 2*s + (uu>>2), j = uu&3;
      g2l16(vsrc + (long)d*(S_*2) + j*16, vB + c*16);
    }
  };

  for (int ph = 0; ph < 2; ++ph){
    const int qt = ph ? (31 - pr) : pr;
    const int q0 = qt * 64;

    // Q fragments: rows q0+R+c16, d = kk*32 + g*8 + 0..7
    v8bf qf[18];
    {
      const char* qgb = (const char*)Qg + (((long)z*S_ + q0 + R + c16)*576 + g*8)*2;
      #pragma unroll
      for (int kk=0;kk<18;kk++) qf[kk] = *(const v8bf*)(qgb + kk*64);
    }
    v4f acc[16];
    #pragma unroll
    for (int i=0;i<16;i++) acc[i] = (v4f){0.f,0.f,0.f,0.f};
    float m[4]  = {-1e30f,-1e30f,-1e30f,-1e30f};
    float lsum[4] = {0.f,0.f,0.f,0.f};

    const int ntile = 2*qt + 2;
    for (int t = 0; t < ntile; ++t){
      __syncthreads();                     // prior tile's LDS readers done
      STAGE(t);
      __syncthreads();                     // staged & visible (implicit vmcnt drain)

      // ---- QK^T: 16 rows x 32 cols, K=576 ----
      v4f s0 = (v4f){0.f,0.f,0.f,0.f}, s1 = (v4f){0.f,0.f,0.f,0.f};
      #pragma unroll
      for (int kk=0;kk<18;kk++){
        int j = kk*4 + g;
        v8bf kf0 = *(const v8bf*)(kB + c16*1152      + ((j ^ (c16&7))<<4));
        v8bf kf1 = *(const v8bf*)(kB + (16+c16)*1152 + ((j ^ (c16&7))<<4));
        s0 = __builtin_amdgcn_mfma_f32_16x16x32_bf16(qf[kk], kf0, s0, 0,0,0);
        s1 = __builtin_amdgcn_mfma_f32_16x16x32_bf16(qf[kk], kf1, s1, 0,0,0);
      }
      // ---- causal mask (last two tiles of this q-tile) ----
      if (t >= ntile-2){
        int kt0 = t*32;
        #pragma unroll
        for (int r=0;r<4;r++){
          int qrow = q0 + R + g*4 + r;
          if (kt0 + c16 > qrow)      s0[r] = -1e30f;
          if (kt0 + 16 + c16 > qrow) s1[r] = -1e30f;
        }
      }
      // ---- wave-private online softmax ----
      float al[4], ps[4];
      #pragma unroll
      for (int r=0;r<4;r++){
        float v = fmaxf(s0[r], s1[r]);
        v = fmaxf(v, __shfl_xor(v, 1)); v = fmaxf(v, __shfl_xor(v, 2));
        v = fmaxf(v, __shfl_xor(v, 4)); v = fmaxf(v, __shfl_xor(v, 8));
        float mn = fmaxf(m[r], v);
        al[r] = __expf(m[r] - mn);
        m[r] = mn;
      }
      #pragma unroll
      for (int r=0;r<4;r++){
        float p0 = __expf(s0[r] - m[r]);
        float p1 = __expf(s1[r] - m[r]);
        int row = g*4 + r;
        int bse = (row>>1)*128;
        int sw  = (row>>1)&7;
        *(unsigned short*)(Pw + bse + (((((row&1)<<2)|(c16>>3)) ^ sw)<<4) + (c16&7)*2) = bfb(p0);
        *(unsigned short*)(Pw + bse + (((((row&1)<<2)|((16+c16)>>3)) ^ sw)<<4) + (c16&7)*2) = bfb(p1);
        float sv = p0 + p1;
        sv += __shfl_xor(sv, 1); sv += __shfl_xor(sv, 2);
        sv += __shfl_xor(sv, 4); sv += __shfl_xor(sv, 8);
        ps[r] = sv;
      }
      #pragma unroll
      for (int r=0;r<4;r++) lsum[r] = lsum[r]*al[r] + ps[r];
      // rescale-skip: al==1 for all rows (no new max) -> skip 64 mults
      if (al[0] != 1.0f || al[1] != 1.0f || al[2] != 1.0f || al[3] != 1.0f){
        #pragma unroll
        for (int cb=0;cb<16;cb++)
          #pragma unroll
          for (int r=0;r<4;r++) acc[cb][r] *= al[r];
      }
      // ---- PV: 16 rows x 256 cols (d-half), K=32 ----
      {
        int prow = c16;
        int au = ((((prow&1)<<2)) | g) ^ ((prow>>1)&7);
        v8bf af = *(const v8bf*)(Pw + (prow>>1)*128 + (au<<4));
        #pragma unroll
        for (int cb=0;cb<16;cb++){
          int d = Dh + cb*16 + c16;
          int vu = ((((d&1)<<2)) | g) ^ ((d>>1)&7);
          v8bf vf = *(const v8bf*)(vB + (d>>1)*128 + (vu<<4));
          acc[cb] = __builtin_amdgcn_mfma_f32_16x16x32_bf16(af, vf, acc[cb], 0,0,0);
        }
      }
    }
    // ---- epilogue ----
    float inv[4];
    #pragma unroll
    for (int r=0;r<4;r++) inv[r] = 1.0f / lsum[r];
    #pragma unroll
    for (int cb=0;cb<16;cb++)
      #pragma unroll
      for (int r=0;r<4;r++){
        int qrow = q0 + R + g*4 + r;
        Og[((long)z*S_ + qrow)*512 + Dh + cb*16 + c16] = __float2bfloat16(acc[cb][r]*inv[r]);
      }
  }
}

// ---------------- launch ----------------------------------------------------
extern "C" void kernel_launch(void* const* d_in, const int* in_sizes, int n_in,
                              void* d_out, int out_size, void* d_ws, size_t ws_size,
                              hipStream_t stream)
{
  const float* hidden = (const float*)d_in[0];
  const float* qn_w   = (const float*)d_in[1];
  const float* qpe_w  = (const float*)d_in[2];
  const float* kva_w  = (const float*)d_in[3];
  const float* ln_w   = (const float*)d_in[4];
  const float* kb_w   = (const float*)d_in[5];
  const float* vb_w   = (const float*)d_in[6];
  const float* o_w    = (const float*)d_in[7];
  const int*   pos    = (const int*)d_in[8];
  float* out = (float*)d_out;
  char* ws = (char*)d_ws;

  float* cosT  = (float*)(ws);                 //    262144
  float* sinT  = (float*)(ws + 262144);        //    262144
  bf16*  ckvb  = (bf16*) (ws + 524288);        //  4718592  (B,S,576) [dead after build_k]
  bf16*  vbb   = (bf16*) (ws + 524288);        //  2097152  alias in ckvb (cast after build_k)
  bf16*  Qb    = (bf16*) (ws + 5242880);       // 75497472  (B*H,S,576) [dead after attn]
  bf16*  ob    = (bf16*) (ws + 5242880);       //  8388608  alias in Qb (cast after attn)
  bf16*  Kb    = (bf16*) (ws + 80740352);      //  4718592  (B,S,576)
  bf16*  outl  = (bf16*) (ws + 85458944);      // 67108864  (B*H,S,512)
  bf16*  qnopeb= (bf16*) (ws + 85458944);      // 16777216  alias in outl (dead pre-attn)
  bf16*  qpeb  = (bf16*) (ws + 102236160);     //  8388608  alias
  bf16*  kbT   = (bf16*) (ws + 110624768);     //  2097152  alias
  bf16*  hb    = (bf16*) (ws + 112721920);     // 16777216  alias
  bf16*  qnb   = (bf16*) (ws + 129499136);     //  8388608  alias
  bf16*  qpw   = (bf16*) (ws + 137887744);     //  4194304  alias
  bf16*  kvab  = (bf16*) (ws + 142082048);     //  2359296  alias (ends 144441344)
  bf16*  voutb = (bf16*) (ws + 152567808);     // 16777216  (B,S,2048)
  bf16*  Kd    = (bf16*) (ws + 169345024);     //  4194304  (B,512,S) ends 173539328

  static_assert(sizeof(v8bf) == 16, "v8bf must be 16B");
  hipFuncSetAttribute((const void*)attn_mfma_kernel,
                      hipFuncAttributeMaxDynamicSharedMemorySize, SMEM_BYTES);

  cossin_kernel<<<256, 256, 0, stream>>>(pos, cosT, sinT);

  // pre-casts to bf16
  castf2b_kernel<<<4096, 256, 0, stream>>>(hidden, hb, 1048576);
  castf2b_kernel<<<2048, 256, 0, stream>>>(qn_w,  qnb, 524288);
  castf2b_kernel<<<1024, 256, 0, stream>>>(qpe_w, qpw, 262144);
  castf2b_kernel<<< 576, 256, 0, stream>>>(kva_w, kvab, 147456);

  // ckv_kpe = hb @ kvab^T   (4096 x 576, K=2048)
  gemm2_kernel<bf16><<<dim3(5,32,1),256,0,stream>>>(
      hb,2048, 1,0,0,  kvab,2048, 1,0,0,  ckvb,576, 1,0,0,  576,2048, 1.f);
  // q_nope = hb @ qnb^T  (4096 x 2048)
  gemm2_kernel<bf16><<<dim3(16,32,1),256,0,stream>>>(
      hb,2048, 1,0,0,  qnb,2048, 1,0,0,  qnopeb,2048, 1,0,0,  2048,2048, 1.f);
  // q_pe = hb @ qpw^T  (4096 x 1024)
  gemm2_kernel<bf16><<<dim3(8,32,1),256,0,stream>>>(
      hb,2048, 1,0,0,  qpw,2048, 1,0,0,  qpeb,1024, 1,0,0,  1024,2048, 1.f);

  kbT_kernel<<<dim3(8,2,16), 256, 0, stream>>>(kb_w, kbT);
  build_k_kernel<<<4096, 256, 0, stream>>>(ckvb, ln_w, cosT, sinT, Kb);
  castf2b_kernel<<<512, 256, 0, stream>>>(vb_w, vbb, 131072);   // into dead ckvb
  tposeV_kernel<<<dim3(8,32,2), 256, 0, stream>>>(Kb, Kd);
  rope_q_kernel<<<8192, 256, 0, stream>>>(qpeb, cosT, sinT, Qb);

  // q_lat = q_nope @ kbT[n]^T  (per (b,n): 2048x512, K=128), *SCALE -> Q[:, :512]
  gemm2_kernel<bf16><<<dim3(4,16,32),256,0,stream>>>(
      qnopeb,2048, 16,(long)S_*2048,128,  kbT,128, 16,0,65536,
      Qb,576, 1,(long)S_*576,0,  512,128, SCALE_F);

  attn_mfma_kernel<<<dim3(512), 512, SMEM_BYTES, stream>>>(Qb, Kb, Kd, outl);

  castf2b_kernel<<<2048, 256, 0, stream>>>(o_w, ob, 524288);    // into dead Qb

  // v_out = out_lat @ vbb[n]^T  (per (b,n): 2048x128, K=512) -> (B,S,H*DV)
  gemm2_kernel<bf16><<<dim3(1,16,32),256,0,stream>>>(
      outl,512, 1,(long)S_*512,0,  vbb,512, 16,0,65536,
      voutb,2048, 16,(long)S_*2048,128,  128,512, 1.f);

  // out = v_out @ ob^T  (4096 x 2048)
  gemm2_kernel<float><<<dim3(16,32,1),256,0,stream>>>(
      voutb,2048, 1,0,0,  ob,2048, 1,0,0,  out,2048, 1,0,0,  2048,2048, 1.f);
}

// Round 11
// 636.461 us; speedup vs baseline: 2.2152x; 2.2152x over previous
//
#include <hip/hip_runtime.h>
#include <hip/hip_bf16.h>

// DeepSeek-V2 MLA prefill, B=2 S=2048 HID=2048 H=16 DN=128 DR=64 KVR=512 DV=128
// Round 11: R9 skeleton frozen (dbuf staging, vmcnt(0)+sync cadence, 512 blocks,
// XCD<->batch map) + QK d-split dedup: each pair-wave computes 288-dim partial,
// exchange via SX; softmax row-split; pair-shared P. 35 vs 53 LDS b128/wave/tile.

typedef __hip_bfloat16 bf16;
typedef __bf16 v8bf __attribute__((ext_vector_type(8)));
typedef float  v4f  __attribute__((ext_vector_type(4)));

#define S_    2048
#define SCALE_F 0.07216878364870322f   // (128+64)^-0.5

__device__ __forceinline__ void st1(float* p, float v){ *p = v; }
__device__ __forceinline__ void st1(bf16* p, float v){ *p = __float2bfloat16(v); }
__device__ __forceinline__ unsigned short bfb(float x){
  return __builtin_bit_cast(unsigned short, __float2bfloat16(x));
}
__device__ __forceinline__ unsigned pk2(float a, float b){
  return (unsigned)bfb(a) | ((unsigned)bfb(b) << 16);
}

// async global->LDS 16B (linear LDS dest = wave-uniform base + lane*16)
typedef const void __attribute__((address_space(1)))* gas_t;
typedef void __attribute__((address_space(3)))* las_t;
__device__ __forceinline__ void g2l16(const void* g, void* l){
  __builtin_amdgcn_global_load_lds((gas_t)g, (las_t)l, 16, 0, 0);
}

// ---------------- cos/sin table: (S,32) each ----------------
__global__ void cossin_kernel(const int* __restrict__ pos, float* __restrict__ cosT,
                              float* __restrict__ sinT){
  int idx = blockIdx.x*256 + threadIdx.x;       // S*32 = 65536
  int i = idx & 31, s = idx >> 5;
  float t = (float)pos[s];
  float freq = t * powf(10000.0f, -(float)i/32.0f);
  cosT[idx] = cosf(freq);
  sinT[idx] = sinf(freq);
}

// ---------------- f32 -> bf16 cast (vector x8) ------------------------------
__global__ void castf2b_kernel(const float* __restrict__ src, bf16* __restrict__ dst, int n8){
  int i = blockIdx.x*256 + threadIdx.x;
  if (i >= n8) return;
  const float4* s = (const float4*)src;
  float4 a = s[2*i], b = s[2*i+1];
  uint4 o; o.x = pk2(a.x,a.y); o.y = pk2(a.z,a.w); o.z = pk2(b.x,b.y); o.w = pk2(b.z,b.w);
  ((uint4*)dst)[i] = o;
}

// ---------------- MFMA GEMM (m97-style): C = A @ W^T ------------------------
// 128x128 tile, BK=32, dbuf LDS via global_load_lds(16B). A,W bf16 row-major.
template<typename TC>
__global__ __launch_bounds__(256) void gemm2_kernel(
    const bf16* __restrict__ A, int lda, int aDiv, long aS1, long aS2,
    const bf16* __restrict__ W, int ldw, int wDiv, long wS1, long wS2,
    TC* __restrict__ C, int ldc, int cDiv, long cS1, long cS2,
    int N, int K, float alpha)
{
  int z = blockIdx.z;
  A += (long)(z/aDiv)*aS1 + (long)(z%aDiv)*aS2;
  W += (long)(z/wDiv)*wS1 + (long)(z%wDiv)*wS2;
  C += (long)(z/cDiv)*cS1 + (long)(z%cDiv)*cS2;
  __shared__ bf16 As[2][4096];
  __shared__ bf16 Ws[2][4096];
  const int tid = threadIdx.x;
  const int w = tid>>6, l = tid&63, g = l>>4, c16 = l&15;
  const int wr = (w>>1)*64, wc = (w&1)*64;
  const int row0 = blockIdx.y*128, col0 = blockIdx.x*128;

  const long aO1 = (long)(row0 + (tid>>2))*lda + (tid&3)*8;
  const long aO2 = (long)(row0 + 64 + (tid>>2))*lda + (tid&3)*8;
  int wr1 = col0 + (tid>>2);      if (wr1 > N-1) wr1 = N-1;
  int wr2 = col0 + 64 + (tid>>2); if (wr2 > N-1) wr2 = N-1;
  const long wO1 = (long)wr1*ldw + (tid&3)*8;
  const long wO2 = (long)wr2*ldw + (tid&3)*8;

  v4f acc[4][4];
  #pragma unroll
  for (int i=0;i<4;i++)
    #pragma unroll
    for (int j=0;j<4;j++) acc[i][j] = (v4f){0.f,0.f,0.f,0.f};

  auto STAGE = [&](int k0, int bsel){
    g2l16(A + aO1 + k0, &As[bsel][tid*8]);
    g2l16(A + aO2 + k0, &As[bsel][2048 + tid*8]);
    g2l16(W + wO1 + k0, &Ws[bsel][tid*8]);
    g2l16(W + wO2 + k0, &Ws[bsel][2048 + tid*8]);
  };
  STAGE(0, 0);
  __syncthreads();
  const int nk = K >> 5;
  for (int t=0; t<nk; ++t){
    const int cur = t & 1;
    if (t+1 < nk) STAGE((t+1)*32, cur^1);
    v8bf af[4], bw[4];
    #pragma unroll
    for (int mi=0;mi<4;mi++) af[mi] = *(const v8bf*)&As[cur][(wr+mi*16+c16)*32 + g*8];
    #pragma unroll
    for (int ni=0;ni<4;ni++) bw[ni] = *(const v8bf*)&Ws[cur][(wc+ni*16+c16)*32 + g*8];
    #pragma unroll
    for (int mi=0;mi<4;mi++)
      #pragma unroll
      for (int ni=0;ni<4;ni++)
        acc[mi][ni] = __builtin_amdgcn_mfma_f32_16x16x32_bf16(af[mi], bw[ni], acc[mi][ni], 0,0,0);
    __syncthreads();
  }
  #pragma unroll
  for (int mi=0;mi<4;mi++)
    #pragma unroll
    for (int ni=0;ni<4;ni++)
      #pragma unroll
      for (int r=0;r<4;r++){
        int row = row0 + wr + mi*16 + g*4 + r;
        int col = col0 + wc + ni*16 + c16;
        if (col < N) st1(C + (long)row*ldc + col, acc[mi][ni][r]*alpha);
      }
}

// ---------------- k_b cast+transpose: (16,128,512)f32 -> (16,512,128)bf16 ----
__global__ __launch_bounds__(256) void kbT_kernel(const float* __restrict__ kb,
                                                  bf16* __restrict__ kbT){
  __shared__ bf16 t[64][65];
  int h = blockIdx.z, c0 = blockIdx.x*64, d0 = blockIdx.y*64;
  const float* src = kb + ((long)h*128 + d0)*512 + c0;
  #pragma unroll
  for (int i=0;i<16;i++){
    int idx = i*256 + threadIdx.x;
    int dl = idx>>6, cl = idx&63;
    t[dl][cl] = __float2bfloat16(src[(long)dl*512 + cl]);
  }
  __syncthreads();
  bf16* dst = kbT + ((long)h*512 + c0)*128 + d0;
  #pragma unroll
  for (int i=0;i<16;i++){
    int idx = i*256 + threadIdx.x;
    int cl = idx>>6, dl = idx&63;
    dst[(long)cl*128 + dl] = t[dl][cl];
  }
}

// ---------------- V transpose: Kb(B,S,576)[:,:512] -> Kd(B,512,S) bf16 ------
__global__ __launch_bounds__(256) void tposeV_kernel(const bf16* __restrict__ Kb,
                                                     bf16* __restrict__ Kd){
  __shared__ bf16 t[64][65];
  int b = blockIdx.z, s0 = blockIdx.y*64, d0 = blockIdx.x*64;
  const bf16* src = Kb + ((long)(b*S_ + s0))*576 + d0;
  #pragma unroll
  for (int i=0;i<16;i++){
    int idx = i*256 + threadIdx.x;
    int sl = idx>>6, dl = idx&63;
    t[sl][dl] = src[(long)sl*576 + dl];
  }
  __syncthreads();
  bf16* dst = Kd + ((long)(b*512 + d0))*S_ + s0;
  #pragma unroll
  for (int i=0;i<16;i++){
    int idx = i*256 + threadIdx.x;
    int dl = idx>>6, sl = idx&63;
    dst[(long)dl*S_ + sl] = t[sl][dl];
  }
}

// ---------------- RMSNorm(ckv) + RoPE(k_pe) -> K bf16 (B,S,576) -------------
__global__ __launch_bounds__(256) void build_k_kernel(
    const bf16* __restrict__ ckv_kpe, const float* __restrict__ ln_w,
    const float* __restrict__ cosT, const float* __restrict__ sinT,
    bf16* __restrict__ Kb)
{
  int row = blockIdx.x;            // b*S + s
  int s = row & (S_-1);
  int tid = threadIdx.x;
  const bf16* src = ckv_kpe + (long)row*576;
  float x0 = __bfloat162float(src[tid*2]), x1 = __bfloat162float(src[tid*2+1]);
  float ss = x0*x0 + x1*x1;
  #pragma unroll
  for (int o=32;o>=1;o>>=1) ss += __shfl_xor(ss, o, 64);
  __shared__ float wss[4];
  int wid = tid>>6, lane = tid&63;
  if (lane==0) wss[wid] = ss;
  __syncthreads();
  float tot = wss[0]+wss[1]+wss[2]+wss[3];
  float rs = rsqrtf(tot*(1.0f/512.0f) + 1e-6f);
  bf16* dst = Kb + (long)row*576;
  dst[tid*2]   = __float2bfloat16(x0*rs*ln_w[tid*2]);
  dst[tid*2+1] = __float2bfloat16(x1*rs*ln_w[tid*2+1]);
  if (tid < 32) {
    float p0 = __bfloat162float(src[512 + tid*2]);
    float p1 = __bfloat162float(src[512 + tid*2 + 1]);
    float c = cosT[s*32+tid], sn = sinT[s*32+tid];
    dst[512+tid] = __float2bfloat16(p0*c - p1*sn);
    dst[544+tid] = __float2bfloat16(p1*c + p0*sn);
  }
}

// ---------------- RoPE(q_pe)*SCALE -> Q cols 512..575 -----------------------
__global__ void rope_q_kernel(const bf16* __restrict__ qpe,
                              const float* __restrict__ cosT, const float* __restrict__ sinT,
                              bf16* __restrict__ Qb)
{
  int idx = blockIdx.x*256 + threadIdx.x;   // B*H*S*32 = 2097152
  int i = idx & 31;
  int s = (idx >> 5) & (S_-1);
  int z = idx >> 16;                        // b*16+n
  int b = z >> 4, n = z & 15;
  long base = ((long)(b*S_+s))*1024 + n*64 + 2*i;
  float x0 = __bfloat162float(qpe[base]), x1 = __bfloat162float(qpe[base+1]);
  float c = cosT[s*32+i], sn = sinT[s*32+i];
  bf16* dst = Qb + ((long)z*S_ + s)*576;
  dst[512+i] = __float2bfloat16((x0*c - x1*sn)*SCALE_F);
  dst[544+i] = __float2bfloat16((x1*c + x0*sn)*SCALE_F);
}

// ---------------- MFMA flash attention (round 11) ----------------------------
// R9 cadence frozen; QK d-split dedup. Wave w: rg=w&3 (16 rows R), dh=w>>2.
// QK: 9 kk over d-half (288 dims) x 32 cols -> partial; exchange partner rows
// via SX; softmax row-split (wave owns r in {2dh, 2dh+1}); P pair-shared.
#define K0_OFF 0
#define K1_OFF 36864
#define V0_OFF 73728
#define V1_OFF 106496
#define SX_OFF 139264     // 4 x 2048
#define P_OFF  147456     // 4 x 1280 (1024 P + 128 alps + pad)
#define SMEM_BYTES 152576

__global__ __launch_bounds__(512, 2) void attn_mfma_kernel(
    const bf16* __restrict__ Qg, const bf16* __restrict__ Kg,
    const bf16* __restrict__ Vdg, bf16* __restrict__ Og)
{
  extern __shared__ char smem[];
  const int tid = threadIdx.x;
  const int w   = tid >> 6;
  const int l   = tid & 63;
  const int g   = l >> 4;
  const int c16 = l & 15;
  const int rg  = w & 3;
  const int dh  = w >> 2;
  const int R   = rg * 16;          // row block within Q tile
  const int Dh  = dh * 256;         // O d half (PV)
  const int DQb = dh * 576;         // QK d-half byte offset (288 elems)
  char* SX = smem + SX_OFF + rg*2048;   // pair-shared partial-S exchange
  char* Pp = smem + P_OFF  + rg*1280;   // pair-shared P + alps

  // XCD-aware mapping: each XCD works on one batch b
  const int lin = blockIdx.x;       // 0..511
  const int k8 = lin & 7;
  const int b  = k8 >> 2;
  const int u  = (lin >> 3)*4 + (k8 & 3);   // 0..255
  const int n  = u & 15;
  const int pr = u >> 4;                    // 0..15 (q-tile pair id)
  const int z  = b*16 + n;

  const char* kb0 = (const char*)Kg  + (long)b*S_*1152;
  const char* vd0 = (const char*)Vdg + (long)b*512*S_*2;

  // stage one 32-row K tile + V tile into LDS (linear dest, pre-swizzled src)
  auto STAGE = [&](int tt, char* kd, char* vd){
    const char* ksrc = kb0 + (long)tt*32*1152;
    #pragma unroll
    for (int it=0; it<4; it++){
      int c = it*512 + tid;                 // 2304 chunks total
      int kcol = c/72, j = c - kcol*72;
      g2l16(ksrc + kcol*1152 + ((j ^ (kcol&7))<<4), kd + c*16);
    }
    if (tid < 256){
      int c = 2048 + tid;
      int kcol = c/72, j = c - kcol*72;
      g2l16(ksrc + kcol*1152 + ((j ^ (kcol&7))<<4), kd + c*16);
    }
    const char* vsrc = vd0 + (long)tt*64;   // kt0*2 bytes
    #pragma unroll
    for (int it=0; it<4; it++){
      int c = it*512 + tid;                 // 2048 chunks
      int s = c>>3, uu = (c&7) ^ (s&7);
      int d = 2*s + (uu>>2), j = uu&3;
      g2l16(vsrc + (long)d*(S_*2) + j*16, vd + c*16);
    }
  };

  for (int ph = 0; ph < 2; ++ph){
    const int qt = ph ? (31 - pr) : pr;
    const int q0 = qt * 64;

    // Q fragments (d-half only): rows q0+R+c16, d = dh*288 + kk*32 + g*8
    v8bf qf[9];
    {
      const char* qgb = (const char*)Qg + ((long)z*S_ + q0 + R + c16)*1152 + DQb;
      #pragma unroll
      for (int kk=0;kk<9;kk++) qf[kk] = *(const v8bf*)(qgb + kk*64 + g*16);
    }
    v4f acc[16];
    #pragma unroll
    for (int i=0;i<16;i++) acc[i] = (v4f){0.f,0.f,0.f,0.f};
    float m2[2] = {-1e30f,-1e30f};        // owned rows r = 2dh, 2dh+1
    float lsum[4] = {0.f,0.f,0.f,0.f};

    const int ntile = 2*qt + 2;
    __syncthreads();                       // prior phase LDS readers done
    STAGE(0, smem + K0_OFF, smem + V0_OFF);

    for (int t = 0; t < ntile; ++t){
      asm volatile("s_waitcnt vmcnt(0)" ::: "memory");
      __syncthreads();                     // buf[t&1] staged & visible
      char* kB = smem + ((t&1) ? K1_OFF : K0_OFF);
      char* vB = smem + ((t&1) ? V1_OFF : V0_OFF);
      if (t+1 < ntile)                     // flies during compute below
        STAGE(t+1, smem + (((t+1)&1) ? K1_OFF : K0_OFF),
                    smem + (((t+1)&1) ? V1_OFF : V0_OFF));

      // ---- QK^T partial: 16 rows x 32 cols over d-half (288) ----
      v4f s0 = (v4f){0.f,0.f,0.f,0.f}, s1 = (v4f){0.f,0.f,0.f,0.f};
      #pragma unroll
      for (int kk=0;kk<9;kk++){
        int j = dh*36 + kk*4 + g;
        v8bf kf0 = *(const v8bf*)(kB + c16*1152      + ((j ^ (c16&7))<<4));
        v8bf kf1 = *(const v8bf*)(kB + (16+c16)*1152 + ((j ^ (c16&7))<<4));
        s0 = __builtin_amdgcn_mfma_f32_16x16x32_bf16(qf[kk], kf0, s0, 0,0,0);
        s1 = __builtin_amdgcn_mfma_f32_16x16x32_bf16(qf[kk], kf1, s1, 0,0,0);
      }
      // ---- send partner-owned rows' partials to SX ----
      {
        const int pr0 = 2*(1-dh);
        #pragma unroll
        for (int rr=0; rr<2; rr++){
          int r = pr0 + rr;
          int row = g*4 + r;
          *(float*)(SX + row*128 + (((c16      + 4*row)&31)<<2)) = s0[r];
          *(float*)(SX + row*128 + (((16 + c16 + 4*row)&31)<<2)) = s1[r];
        }
      }
      asm volatile("s_waitcnt lgkmcnt(0)" ::: "memory");
      __builtin_amdgcn_s_barrier();
      __builtin_amdgcn_sched_barrier(0);
      // ---- combine own rows, mask, softmax, publish P + alps ----
      {
        const int or0 = 2*dh;
        #pragma unroll
        for (int rr=0; rr<2; rr++){
          int r = or0 + rr;
          int row = g*4 + r;
          float v0 = s0[r] + *(const float*)(SX + row*128 + (((c16      + 4*row)&31)<<2));
          float v1 = s1[r] + *(const float*)(SX + row*128 + (((16 + c16 + 4*row)&31)<<2));
          if (t >= ntile-2){
            int kt0 = t*32;
            int qrow = q0 + R + row;
            if (kt0 + c16 > qrow)      v0 = -1e30f;
            if (kt0 + 16 + c16 > qrow) v1 = -1e30f;
          }
          float pm = fmaxf(v0, v1);
          pm = fmaxf(pm, __shfl_xor(pm, 1)); pm = fmaxf(pm, __shfl_xor(pm, 2));
          pm = fmaxf(pm, __shfl_xor(pm, 4)); pm = fmaxf(pm, __shfl_xor(pm, 8));
          float mn = fmaxf(m2[rr], pm);
          float alv = __expf(m2[rr] - mn);
          m2[rr] = mn;
          float p0 = __expf(v0 - mn);
          float p1 = __expf(v1 - mn);
          int bse = (row>>1)*128;
          int sw  = (row>>1)&7;
          *(unsigned short*)(Pp + bse + (((((row&1)<<2)|(c16>>3)) ^ sw)<<4) + (c16&7)*2) = bfb(p0);
          *(unsigned short*)(Pp + bse + (((((row&1)<<2)|(2+(c16>>3))) ^ sw)<<4) + (c16&7)*2) = bfb(p1);
          float sv = p0 + p1;
          sv += __shfl_xor(sv, 1); sv += __shfl_xor(sv, 2);
          sv += __shfl_xor(sv, 4); sv += __shfl_xor(sv, 8);
          if (c16 == 0) *(float2*)(Pp + 1024 + row*8) = make_float2(alv, sv);
        }
      }
      asm volatile("s_waitcnt lgkmcnt(0)" ::: "memory");
      __builtin_amdgcn_s_barrier();
      __builtin_amdgcn_sched_barrier(0);
      // ---- rescale + lsum (all 4 r via published alps), then PV ----
      {
        float ax[4];
        #pragma unroll
        for (int r=0;r<4;r++){
          float2 ap = *(const float2*)(Pp + 1024 + (g*4+r)*8);
          lsum[r] = lsum[r]*ap.x + ap.y;
          ax[r] = ap.x;
        }
        if (ax[0]!=1.0f || ax[1]!=1.0f || ax[2]!=1.0f || ax[3]!=1.0f){
          #pragma unroll
          for (int cb=0;cb<16;cb++)
            #pragma unroll
            for (int r=0;r<4;r++) acc[cb][r] *= ax[r];
        }
        int prow = c16;
        int au = ((((prow&1)<<2)) | g) ^ ((prow>>1)&7);
        v8bf af = *(const v8bf*)(Pp + (prow>>1)*128 + (au<<4));
        #pragma unroll
        for (int cb=0;cb<16;cb++){
          int d = Dh + cb*16 + c16;
          int vu = ((((d&1)<<2)) | g) ^ ((d>>1)&7);
          v8bf vf = *(const v8bf*)(vB + (d>>1)*128 + (vu<<4));
          acc[cb] = __builtin_amdgcn_mfma_f32_16x16x32_bf16(af, vf, acc[cb], 0,0,0);
        }
      }
    }
    // ---- epilogue ----
    float inv[4];
    #pragma unroll
    for (int r=0;r<4;r++) inv[r] = 1.0f / lsum[r];
    #pragma unroll
    for (int cb=0;cb<16;cb++)
      #pragma unroll
      for (int r=0;r<4;r++){
        int qrow = q0 + R + g*4 + r;
        Og[((long)z*S_ + qrow)*512 + Dh + cb*16 + c16] = __float2bfloat16(acc[cb][r]*inv[r]);
      }
  }
}

// ---------------- launch ----------------------------------------------------
extern "C" void kernel_launch(void* const* d_in, const int* in_sizes, int n_in,
                              void* d_out, int out_size, void* d_ws, size_t ws_size,
                              hipStream_t stream)
{
  const float* hidden = (const float*)d_in[0];
  const float* qn_w   = (const float*)d_in[1];
  const float* qpe_w  = (const float*)d_in[2];
  const float* kva_w  = (const float*)d_in[3];
  const float* ln_w   = (const float*)d_in[4];
  const float* kb_w   = (const float*)d_in[5];
  const float* vb_w   = (const float*)d_in[6];
  const float* o_w    = (const float*)d_in[7];
  const int*   pos    = (const int*)d_in[8];
  float* out = (float*)d_out;
  char* ws = (char*)d_ws;

  float* cosT  = (float*)(ws);                 //    262144
  float* sinT  = (float*)(ws + 262144);        //    262144
  bf16*  ckvb  = (bf16*) (ws + 524288);        //  4718592  (B,S,576) [dead after build_k]
  bf16*  vbb   = (bf16*) (ws + 524288);        //  2097152  alias in ckvb (cast after build_k)
  bf16*  Qb    = (bf16*) (ws + 5242880);       // 75497472  (B*H,S,576) [dead after attn]
  bf16*  ob    = (bf16*) (ws + 5242880);       //  8388608  alias in Qb (cast after attn)
  bf16*  Kb    = (bf16*) (ws + 80740352);      //  4718592  (B,S,576)
  bf16*  outl  = (bf16*) (ws + 85458944);      // 67108864  (B*H,S,512)
  bf16*  qnopeb= (bf16*) (ws + 85458944);      // 16777216  alias in outl (dead pre-attn)
  bf16*  qpeb  = (bf16*) (ws + 102236160);     //  8388608  alias
  bf16*  kbT   = (bf16*) (ws + 110624768);     //  2097152  alias
  bf16*  hb    = (bf16*) (ws + 112721920);     // 16777216  alias
  bf16*  qnb   = (bf16*) (ws + 129499136);     //  8388608  alias
  bf16*  qpw   = (bf16*) (ws + 137887744);     //  4194304  alias
  bf16*  kvab  = (bf16*) (ws + 142082048);     //  2359296  alias (ends 144441344)
  bf16*  voutb = (bf16*) (ws + 152567808);     // 16777216  (B,S,2048)
  bf16*  Kd    = (bf16*) (ws + 169345024);     //  4194304  (B,512,S) ends 173539328

  static_assert(sizeof(v8bf) == 16, "v8bf must be 16B");
  hipFuncSetAttribute((const void*)attn_mfma_kernel,
                      hipFuncAttributeMaxDynamicSharedMemorySize, SMEM_BYTES);

  cossin_kernel<<<256, 256, 0, stream>>>(pos, cosT, sinT);

  // pre-casts to bf16
  castf2b_kernel<<<4096, 256, 0, stream>>>(hidden, hb, 1048576);
  castf2b_kernel<<<2048, 256, 0, stream>>>(qn_w,  qnb, 524288);
  castf2b_kernel<<<1024, 256, 0, stream>>>(qpe_w, qpw, 262144);
  castf2b_kernel<<< 576, 256, 0, stream>>>(kva_w, kvab, 147456);

  // ckv_kpe = hb @ kvab^T   (4096 x 576, K=2048)
  gemm2_kernel<bf16><<<dim3(5,32,1),256,0,stream>>>(
      hb,2048, 1,0,0,  kvab,2048, 1,0,0,  ckvb,576, 1,0,0,  576,2048, 1.f);
  // q_nope = hb @ qnb^T  (4096 x 2048)
  gemm2_kernel<bf16><<<dim3(16,32,1),256,0,stream>>>(
      hb,2048, 1,0,0,  qnb,2048, 1,0,0,  qnopeb,2048, 1,0,0,  2048,2048, 1.f);
  // q_pe = hb @ qpw^T  (4096 x 1024)
  gemm2_kernel<bf16><<<dim3(8,32,1),256,0,stream>>>(
      hb,2048, 1,0,0,  qpw,2048, 1,0,0,  qpeb,1024, 1,0,0,  1024,2048, 1.f);

  kbT_kernel<<<dim3(8,2,16), 256, 0, stream>>>(kb_w, kbT);
  build_k_kernel<<<4096, 256, 0, stream>>>(ckvb, ln_w, cosT, sinT, Kb);
  castf2b_kernel<<<512, 256, 0, stream>>>(vb_w, vbb, 131072);   // into dead ckvb
  tposeV_kernel<<<dim3(8,32,2), 256, 0, stream>>>(Kb, Kd);
  rope_q_kernel<<<8192, 256, 0, stream>>>(qpeb, cosT, sinT, Qb);

  // q_lat = q_nope @ kbT[n]^T  (per (b,n): 2048x512, K=128), *SCALE -> Q[:, :512]
  gemm2_kernel<bf16><<<dim3(4,16,32),256,0,stream>>>(
      qnopeb,2048, 16,(long)S_*2048,128,  kbT,128, 16,0,65536,
      Qb,576, 1,(long)S_*576,0,  512,128, SCALE_F);

  attn_mfma_kernel<<<dim3(512), 512, SMEM_BYTES, stream>>>(Qb, Kb, Kd, outl);

  castf2b_kernel<<<2048, 256, 0, stream>>>(o_w, ob, 524288);    // into dead Qb

  // v_out = out_lat @ vbb[n]^T  (per (b,n): 2048x128, K=512) -> (B,S,H*DV)
  gemm2_kernel<bf16><<<dim3(1,16,32),256,0,stream>>>(
      outl,512, 1,(long)S_*512,0,  vbb,512, 16,0,65536,
      voutb,2048, 16,(long)S_*2048,128,  128,512, 1.f);

  // out = v_out @ ob^T  (4096 x 2048)
  gemm2_kernel<float><<<dim3(16,32,1),256,0,stream>>>(
      voutb,2048, 1,0,0,  ob,2048, 1,0,0,  out,2048, 1,0,0,  2048,2048, 1.f);
}

// Round 12
// 601.477 us; speedup vs baseline: 2.3441x; 1.0582x over previous
//
#include <hip/hip_runtime.h>
#include <hip/hip_bf16.h>

// DeepSeek-V2 MLA prefill, B=2 S=2048 HID=2048 H=16 DN=128 DR=64 KVR=512 DV=128
// Round 12: R11 attn + hoisted staging addresses + defer-max (THR=8) rescale
// skip; 3 projection GEMMs fused into one dispatch (proj3).

typedef __hip_bfloat16 bf16;
typedef __bf16 v8bf __attribute__((ext_vector_type(8)));
typedef float  v4f  __attribute__((ext_vector_type(4)));

#define S_    2048
#define SCALE_F 0.07216878364870322f   // (128+64)^-0.5

__device__ __forceinline__ void st1(float* p, float v){ *p = v; }
__device__ __forceinline__ void st1(bf16* p, float v){ *p = __float2bfloat16(v); }
__device__ __forceinline__ unsigned short bfb(float x){
  return __builtin_bit_cast(unsigned short, __float2bfloat16(x));
}
__device__ __forceinline__ unsigned pk2(float a, float b){
  return (unsigned)bfb(a) | ((unsigned)bfb(b) << 16);
}

// async global->LDS 16B (linear LDS dest = wave-uniform base + lane*16)
typedef const void __attribute__((address_space(1)))* gas_t;
typedef void __attribute__((address_space(3)))* las_t;
__device__ __forceinline__ void g2l16(const void* g, void* l){
  __builtin_amdgcn_global_load_lds((gas_t)g, (las_t)l, 16, 0, 0);
}

// ---------------- cos/sin table: (S,32) each ----------------
__global__ void cossin_kernel(const int* __restrict__ pos, float* __restrict__ cosT,
                              float* __restrict__ sinT){
  int idx = blockIdx.x*256 + threadIdx.x;       // S*32 = 65536
  int i = idx & 31, s = idx >> 5;
  float t = (float)pos[s];
  float freq = t * powf(10000.0f, -(float)i/32.0f);
  cosT[idx] = cosf(freq);
  sinT[idx] = sinf(freq);
}

// ---------------- f32 -> bf16 cast (vector x8) ------------------------------
__global__ void castf2b_kernel(const float* __restrict__ src, bf16* __restrict__ dst, int n8){
  int i = blockIdx.x*256 + threadIdx.x;
  if (i >= n8) return;
  const float4* s = (const float4*)src;
  float4 a = s[2*i], b = s[2*i+1];
  uint4 o; o.x = pk2(a.x,a.y); o.y = pk2(a.z,a.w); o.z = pk2(b.x,b.y); o.w = pk2(b.z,b.w);
  ((uint4*)dst)[i] = o;
}

// ---------------- MFMA GEMM (m97-style): C = A @ W^T ------------------------
// 128x128 tile, BK=32, dbuf LDS via global_load_lds(16B). A,W bf16 row-major.
template<typename TC>
__global__ __launch_bounds__(256) void gemm2_kernel(
    const bf16* __restrict__ A, int lda, int aDiv, long aS1, long aS2,
    const bf16* __restrict__ W, int ldw, int wDiv, long wS1, long wS2,
    TC* __restrict__ C, int ldc, int cDiv, long cS1, long cS2,
    int N, int K, float alpha)
{
  int z = blockIdx.z;
  A += (long)(z/aDiv)*aS1 + (long)(z%aDiv)*aS2;
  W += (long)(z/wDiv)*wS1 + (long)(z%wDiv)*wS2;
  C += (long)(z/cDiv)*cS1 + (long)(z%cDiv)*cS2;
  __shared__ bf16 As[2][4096];
  __shared__ bf16 Ws[2][4096];
  const int tid = threadIdx.x;
  const int w = tid>>6, l = tid&63, g = l>>4, c16 = l&15;
  const int wr = (w>>1)*64, wc = (w&1)*64;
  const int row0 = blockIdx.y*128, col0 = blockIdx.x*128;

  const long aO1 = (long)(row0 + (tid>>2))*lda + (tid&3)*8;
  const long aO2 = (long)(row0 + 64 + (tid>>2))*lda + (tid&3)*8;
  int wr1 = col0 + (tid>>2);      if (wr1 > N-1) wr1 = N-1;
  int wr2 = col0 + 64 + (tid>>2); if (wr2 > N-1) wr2 = N-1;
  const long wO1 = (long)wr1*ldw + (tid&3)*8;
  const long wO2 = (long)wr2*ldw + (tid&3)*8;

  v4f acc[4][4];
  #pragma unroll
  for (int i=0;i<4;i++)
    #pragma unroll
    for (int j=0;j<4;j++) acc[i][j] = (v4f){0.f,0.f,0.f,0.f};

  auto STAGE = [&](int k0, int bsel){
    g2l16(A + aO1 + k0, &As[bsel][tid*8]);
    g2l16(A + aO2 + k0, &As[bsel][2048 + tid*8]);
    g2l16(W + wO1 + k0, &Ws[bsel][tid*8]);
    g2l16(W + wO2 + k0, &Ws[bsel][2048 + tid*8]);
  };
  STAGE(0, 0);
  __syncthreads();
  const int nk = K >> 5;
  for (int t=0; t<nk; ++t){
    const int cur = t & 1;
    if (t+1 < nk) STAGE((t+1)*32, cur^1);
    v8bf af[4], bw[4];
    #pragma unroll
    for (int mi=0;mi<4;mi++) af[mi] = *(const v8bf*)&As[cur][(wr+mi*16+c16)*32 + g*8];
    #pragma unroll
    for (int ni=0;ni<4;ni++) bw[ni] = *(const v8bf*)&Ws[cur][(wc+ni*16+c16)*32 + g*8];
    #pragma unroll
    for (int mi=0;mi<4;mi++)
      #pragma unroll
      for (int ni=0;ni<4;ni++)
        acc[mi][ni] = __builtin_amdgcn_mfma_f32_16x16x32_bf16(af[mi], bw[ni], acc[mi][ni], 0,0,0);
    __syncthreads();
  }
  #pragma unroll
  for (int mi=0;mi<4;mi++)
    #pragma unroll
    for (int ni=0;ni<4;ni++)
      #pragma unroll
      for (int r=0;r<4;r++){
        int row = row0 + wr + mi*16 + g*4 + r;
        int col = col0 + wc + ni*16 + c16;
        if (col < N) st1(C + (long)row*ldc + col, acc[mi][ni][r]*alpha);
      }
}

// ---------------- fused projections: {q_nope, q_pe, ckv} = hb @ W^T ----------
// bx<16 -> q_nope col-tile; 16..23 -> q_pe; 24..28 -> ckv. A=hb (4096,2048).
__global__ __launch_bounds__(256) void proj3_kernel(
    const bf16* __restrict__ A,
    const bf16* __restrict__ Wq, const bf16* __restrict__ Wp, const bf16* __restrict__ Wc,
    bf16* __restrict__ Cq, bf16* __restrict__ Cp, bf16* __restrict__ Cc)
{
  const int bx = blockIdx.x;
  const bf16* W; bf16* C; int ldc, N, col0;
  if (bx < 16){ W = Wq; C = Cq; ldc = 2048; N = 2048; col0 = bx*128; }
  else if (bx < 24){ W = Wp; C = Cp; ldc = 1024; N = 1024; col0 = (bx-16)*128; }
  else { W = Wc; C = Cc; ldc = 576; N = 576; col0 = (bx-24)*128; }
  __shared__ bf16 As[2][4096];
  __shared__ bf16 Ws[2][4096];
  const int tid = threadIdx.x;
  const int w = tid>>6, l = tid&63, g = l>>4, c16 = l&15;
  const int wr = (w>>1)*64, wc = (w&1)*64;
  const int row0 = blockIdx.y*128;

  const long aO1 = (long)(row0 + (tid>>2))*2048 + (tid&3)*8;
  const long aO2 = (long)(row0 + 64 + (tid>>2))*2048 + (tid&3)*8;
  int wr1 = col0 + (tid>>2);      if (wr1 > N-1) wr1 = N-1;
  int wr2 = col0 + 64 + (tid>>2); if (wr2 > N-1) wr2 = N-1;
  const long wO1 = (long)wr1*2048 + (tid&3)*8;
  const long wO2 = (long)wr2*2048 + (tid&3)*8;

  v4f acc[4][4];
  #pragma unroll
  for (int i=0;i<4;i++)
    #pragma unroll
    for (int j=0;j<4;j++) acc[i][j] = (v4f){0.f,0.f,0.f,0.f};

  auto STAGE = [&](int k0, int bsel){
    g2l16(A + aO1 + k0, &As[bsel][tid*8]);
    g2l16(A + aO2 + k0, &As[bsel][2048 + tid*8]);
    g2l16(W + wO1 + k0, &Ws[bsel][tid*8]);
    g2l16(W + wO2 + k0, &Ws[bsel][2048 + tid*8]);
  };
  STAGE(0, 0);
  __syncthreads();
  for (int t=0; t<64; ++t){
    const int cur = t & 1;
    if (t+1 < 64) STAGE((t+1)*32, cur^1);
    v8bf af[4], bw[4];
    #pragma unroll
    for (int mi=0;mi<4;mi++) af[mi] = *(const v8bf*)&As[cur][(wr+mi*16+c16)*32 + g*8];
    #pragma unroll
    for (int ni=0;ni<4;ni++) bw[ni] = *(const v8bf*)&Ws[cur][(wc+ni*16+c16)*32 + g*8];
    #pragma unroll
    for (int mi=0;mi<4;mi++)
      #pragma unroll
      for (int ni=0;ni<4;ni++)
        acc[mi][ni] = __builtin_amdgcn_mfma_f32_16x16x32_bf16(af[mi], bw[ni], acc[mi][ni], 0,0,0);
    __syncthreads();
  }
  #pragma unroll
  for (int mi=0;mi<4;mi++)
    #pragma unroll
    for (int ni=0;ni<4;ni++)
      #pragma unroll
      for (int r=0;r<4;r++){
        int row = row0 + wr + mi*16 + g*4 + r;
        int col = col0 + wc + ni*16 + c16;
        if (col < N) C[(long)row*ldc + col] = __float2bfloat16(acc[mi][ni][r]);
      }
}

// ---------------- k_b cast+transpose: (16,128,512)f32 -> (16,512,128)bf16 ----
__global__ __launch_bounds__(256) void kbT_kernel(const float* __restrict__ kb,
                                                  bf16* __restrict__ kbT){
  __shared__ bf16 t[64][65];
  int h = blockIdx.z, c0 = blockIdx.x*64, d0 = blockIdx.y*64;
  const float* src = kb + ((long)h*128 + d0)*512 + c0;
  #pragma unroll
  for (int i=0;i<16;i++){
    int idx = i*256 + threadIdx.x;
    int dl = idx>>6, cl = idx&63;
    t[dl][cl] = __float2bfloat16(src[(long)dl*512 + cl]);
  }
  __syncthreads();
  bf16* dst = kbT + ((long)h*512 + c0)*128 + d0;
  #pragma unroll
  for (int i=0;i<16;i++){
    int idx = i*256 + threadIdx.x;
    int cl = idx>>6, dl = idx&63;
    dst[(long)cl*128 + dl] = t[dl][cl];
  }
}

// ---------------- V transpose: Kb(B,S,576)[:,:512] -> Kd(B,512,S) bf16 ------
__global__ __launch_bounds__(256) void tposeV_kernel(const bf16* __restrict__ Kb,
                                                     bf16* __restrict__ Kd){
  __shared__ bf16 t[64][65];
  int b = blockIdx.z, s0 = blockIdx.y*64, d0 = blockIdx.x*64;
  const bf16* src = Kb + ((long)(b*S_ + s0))*576 + d0;
  #pragma unroll
  for (int i=0;i<16;i++){
    int idx = i*256 + threadIdx.x;
    int sl = idx>>6, dl = idx&63;
    t[sl][dl] = src[(long)sl*576 + dl];
  }
  __syncthreads();
  bf16* dst = Kd + ((long)(b*512 + d0))*S_ + s0;
  #pragma unroll
  for (int i=0;i<16;i++){
    int idx = i*256 + threadIdx.x;
    int dl = idx>>6, sl = idx&63;
    dst[(long)dl*S_ + sl] = t[sl][dl];
  }
}

// ---------------- RMSNorm(ckv) + RoPE(k_pe) -> K bf16 (B,S,576) -------------
__global__ __launch_bounds__(256) void build_k_kernel(
    const bf16* __restrict__ ckv_kpe, const float* __restrict__ ln_w,
    const float* __restrict__ cosT, const float* __restrict__ sinT,
    bf16* __restrict__ Kb)
{
  int row = blockIdx.x;            // b*S + s
  int s = row & (S_-1);
  int tid = threadIdx.x;
  const bf16* src = ckv_kpe + (long)row*576;
  float x0 = __bfloat162float(src[tid*2]), x1 = __bfloat162float(src[tid*2+1]);
  float ss = x0*x0 + x1*x1;
  #pragma unroll
  for (int o=32;o>=1;o>>=1) ss += __shfl_xor(ss, o, 64);
  __shared__ float wss[4];
  int wid = tid>>6, lane = tid&63;
  if (lane==0) wss[wid] = ss;
  __syncthreads();
  float tot = wss[0]+wss[1]+wss[2]+wss[3];
  float rs = rsqrtf(tot*(1.0f/512.0f) + 1e-6f);
  bf16* dst = Kb + (long)row*576;
  dst[tid*2]   = __float2bfloat16(x0*rs*ln_w[tid*2]);
  dst[tid*2+1] = __float2bfloat16(x1*rs*ln_w[tid*2+1]);
  if (tid < 32) {
    float p0 = __bfloat162float(src[512 + tid*2]);
    float p1 = __bfloat162float(src[512 + tid*2 + 1]);
    float c = cosT[s*32+tid], sn = sinT[s*32+tid];
    dst[512+tid] = __float2bfloat16(p0*c - p1*sn);
    dst[544+tid] = __float2bfloat16(p1*c + p0*sn);
  }
}

// ---------------- RoPE(q_pe)*SCALE -> Q cols 512..575 -----------------------
__global__ void rope_q_kernel(const bf16* __restrict__ qpe,
                              const float* __restrict__ cosT, const float* __restrict__ sinT,
                              bf16* __restrict__ Qb)
{
  int idx = blockIdx.x*256 + threadIdx.x;   // B*H*S*32 = 2097152
  int i = idx & 31;
  int s = (idx >> 5) & (S_-1);
  int z = idx >> 16;                        // b*16+n
  int b = z >> 4, n = z & 15;
  long base = ((long)(b*S_+s))*1024 + n*64 + 2*i;
  float x0 = __bfloat162float(qpe[base]), x1 = __bfloat162float(qpe[base+1]);
  float c = cosT[s*32+i], sn = sinT[s*32+i];
  bf16* dst = Qb + ((long)z*S_ + s)*576;
  dst[512+i] = __float2bfloat16((x0*c - x1*sn)*SCALE_F);
  dst[544+i] = __float2bfloat16((x1*c + x0*sn)*SCALE_F);
}

// ---------------- MFMA flash attention (round 12) ----------------------------
// R11 structure + hoisted staging addresses + defer-max (THR=8).
#define K0_OFF 0
#define K1_OFF 36864
#define V0_OFF 73728
#define V1_OFF 106496
#define SX_OFF 139264     // 4 x 2048
#define P_OFF  147456     // 4 x 1280 (1024 P + 128 alps + pad)
#define SMEM_BYTES 152576

__global__ __launch_bounds__(512, 2) void attn_mfma_kernel(
    const bf16* __restrict__ Qg, const bf16* __restrict__ Kg,
    const bf16* __restrict__ Vdg, bf16* __restrict__ Og)
{
  extern __shared__ char smem[];
  const int tid = threadIdx.x;
  const int w   = tid >> 6;
  const int l   = tid & 63;
  const int g   = l >> 4;
  const int c16 = l & 15;
  const int rg  = w & 3;
  const int dh  = w >> 2;
  const int R   = rg * 16;          // row block within Q tile
  const int Dh  = dh * 256;         // O d half (PV)
  const int DQb = dh * 576;         // QK d-half byte offset (288 elems)
  char* SX = smem + SX_OFF + rg*2048;   // pair-shared partial-S exchange
  char* Pp = smem + P_OFF  + rg*1280;   // pair-shared P + alps

  // XCD-aware mapping: each XCD works on one batch b
  const int lin = blockIdx.x;       // 0..511
  const int k8 = lin & 7;
  const int b  = k8 >> 2;
  const int u  = (lin >> 3)*4 + (k8 & 3);   // 0..255
  const int n  = u & 15;
  const int pr = u >> 4;                    // 0..15 (q-tile pair id)
  const int z  = b*16 + n;

  const char* kb0 = (const char*)Kg  + (long)b*S_*1152;
  const char* vd0 = (const char*)Vdg + (long)b*512*S_*2;

  // ---- hoisted staging offsets (tid-only, loop-invariant) ----
  int kOffG[5], kOffL[5], vOffG[4], vOffL[4];
  #pragma unroll
  for (int it=0; it<4; it++){
    int c = it*512 + tid;
    int kcol = c/72, j = c - kcol*72;
    kOffG[it] = kcol*1152 + ((j ^ (kcol&7))<<4);
    kOffL[it] = c*16;
  }
  {
    int c = 2048 + tid;
    int kcol = c/72, j = c - kcol*72;
    kOffG[4] = kcol*1152 + ((j ^ (kcol&7))<<4);
    kOffL[4] = c*16;
  }
  #pragma unroll
  for (int it=0; it<4; it++){
    int c = it*512 + tid;
    int s = c>>3, uu = (c&7) ^ (s&7);
    int d = 2*s + (uu>>2), j = uu&3;
    vOffG[it] = d*(S_*2) + j*16;
    vOffL[it] = c*16;
  }

  auto STAGE = [&](int tt, char* kd, char* vd){
    const char* ksrc = kb0 + (long)tt*36864;
    #pragma unroll
    for (int it=0; it<4; it++) g2l16(ksrc + kOffG[it], kd + kOffL[it]);
    if (tid < 256) g2l16(ksrc + kOffG[4], kd + kOffL[4]);
    const char* vsrc = vd0 + (long)tt*64;
    #pragma unroll
    for (int it=0; it<4; it++) g2l16(vsrc + vOffG[it], vd + vOffL[it]);
  };

  for (int ph = 0; ph < 2; ++ph){
    const int qt = ph ? (31 - pr) : pr;
    const int q0 = qt * 64;

    // Q fragments (d-half only): rows q0+R+c16, d = dh*288 + kk*32 + g*8
    v8bf qf[9];
    {
      const char* qgb = (const char*)Qg + ((long)z*S_ + q0 + R + c16)*1152 + DQb;
      #pragma unroll
      for (int kk=0;kk<9;kk++) qf[kk] = *(const v8bf*)(qgb + kk*64 + g*16);
    }
    v4f acc[16];
    #pragma unroll
    for (int i=0;i<16;i++) acc[i] = (v4f){0.f,0.f,0.f,0.f};
    float m2[2] = {-1e30f,-1e30f};        // owned rows r = 2dh, 2dh+1
    float lsum[4] = {0.f,0.f,0.f,0.f};

    const int ntile = 2*qt + 2;
    __syncthreads();                       // prior phase LDS readers done
    STAGE(0, smem + K0_OFF, smem + V0_OFF);

    for (int t = 0; t < ntile; ++t){
      asm volatile("s_waitcnt vmcnt(0)" ::: "memory");
      __syncthreads();                     // buf[t&1] staged & visible
      char* kB = smem + ((t&1) ? K1_OFF : K0_OFF);
      char* vB = smem + ((t&1) ? V1_OFF : V0_OFF);
      if (t+1 < ntile)                     // flies during compute below
        STAGE(t+1, smem + (((t+1)&1) ? K1_OFF : K0_OFF),
                    smem + (((t+1)&1) ? V1_OFF : V0_OFF));

      // ---- QK^T partial: 16 rows x 32 cols over d-half (288) ----
      v4f s0 = (v4f){0.f,0.f,0.f,0.f}, s1 = (v4f){0.f,0.f,0.f,0.f};
      #pragma unroll
      for (int kk=0;kk<9;kk++){
        int j = dh*36 + kk*4 + g;
        v8bf kf0 = *(const v8bf*)(kB + c16*1152      + ((j ^ (c16&7))<<4));
        v8bf kf1 = *(const v8bf*)(kB + (16+c16)*1152 + ((j ^ (c16&7))<<4));
        s0 = __builtin_amdgcn_mfma_f32_16x16x32_bf16(qf[kk], kf0, s0, 0,0,0);
        s1 = __builtin_amdgcn_mfma_f32_16x16x32_bf16(qf[kk], kf1, s1, 0,0,0);
      }
      // ---- send partner-owned rows' partials to SX ----
      {
        const int pr0 = 2*(1-dh);
        #pragma unroll
        for (int rr=0; rr<2; rr++){
          int r = pr0 + rr;
          int row = g*4 + r;
          *(float*)(SX + row*128 + (((c16      + 4*row)&31)<<2)) = s0[r];
          *(float*)(SX + row*128 + (((16 + c16 + 4*row)&31)<<2)) = s1[r];
        }
      }
      asm volatile("s_waitcnt lgkmcnt(0)" ::: "memory");
      __builtin_amdgcn_s_barrier();
      __builtin_amdgcn_sched_barrier(0);
      // ---- combine own rows, mask, softmax (defer-max THR=8), publish ----
      {
        const int or0 = 2*dh;
        #pragma unroll
        for (int rr=0; rr<2; rr++){
          int r = or0 + rr;
          int row = g*4 + r;
          float v0 = s0[r] + *(const float*)(SX + row*128 + (((c16      + 4*row)&31)<<2));
          float v1 = s1[r] + *(const float*)(SX + row*128 + (((16 + c16 + 4*row)&31)<<2));
          if (t >= ntile-2){
            int kt0 = t*32;
            int qrow = q0 + R + row;
            if (kt0 + c16 > qrow)      v0 = -1e30f;
            if (kt0 + 16 + c16 > qrow) v1 = -1e30f;
          }
          float pm = fmaxf(v0, v1);
          pm = fmaxf(pm, __shfl_xor(pm, 1)); pm = fmaxf(pm, __shfl_xor(pm, 2));
          pm = fmaxf(pm, __shfl_xor(pm, 4)); pm = fmaxf(pm, __shfl_xor(pm, 8));
          float alv = 1.0f;
          if (pm > m2[rr] + 8.0f){            // defer-max: only rescale on big growth
            alv = __expf(m2[rr] - pm);
            m2[rr] = pm;
          }
          float p0 = __expf(v0 - m2[rr]);
          float p1 = __expf(v1 - m2[rr]);
          int bse = (row>>1)*128;
          int sw  = (row>>1)&7;
          *(unsigned short*)(Pp + bse + (((((row&1)<<2)|(c16>>3)) ^ sw)<<4) + (c16&7)*2) = bfb(p0);
          *(unsigned short*)(Pp + bse + (((((row&1)<<2)|(2+(c16>>3))) ^ sw)<<4) + (c16&7)*2) = bfb(p1);
          float sv = p0 + p1;
          sv += __shfl_xor(sv, 1); sv += __shfl_xor(sv, 2);
          sv += __shfl_xor(sv, 4); sv += __shfl_xor(sv, 8);
          if (c16 == 0) *(float2*)(Pp + 1024 + row*8) = make_float2(alv, sv);
        }
      }
      asm volatile("s_waitcnt lgkmcnt(0)" ::: "memory");
      __builtin_amdgcn_s_barrier();
      __builtin_amdgcn_sched_barrier(0);
      // ---- rescale + lsum (all 4 r via published alps), then PV ----
      {
        float ax[4];
        #pragma unroll
        for (int r=0;r<4;r++){
          float2 ap = *(const float2*)(Pp + 1024 + (g*4+r)*8);
          lsum[r] = lsum[r]*ap.x + ap.y;
          ax[r] = ap.x;
        }
        if (ax[0]!=1.0f || ax[1]!=1.0f || ax[2]!=1.0f || ax[3]!=1.0f){
          #pragma unroll
          for (int cb=0;cb<16;cb++)
            #pragma unroll
            for (int r=0;r<4;r++) acc[cb][r] *= ax[r];
        }
        int prow = c16;
        int au = ((((prow&1)<<2)) | g) ^ ((prow>>1)&7);
        v8bf af = *(const v8bf*)(Pp + (prow>>1)*128 + (au<<4));
        #pragma unroll
        for (int cb=0;cb<16;cb++){
          int d = Dh + cb*16 + c16;
          int vu = ((((d&1)<<2)) | g) ^ ((d>>1)&7);
          v8bf vf = *(const v8bf*)(vB + (d>>1)*128 + (vu<<4));
          acc[cb] = __builtin_amdgcn_mfma_f32_16x16x32_bf16(af, vf, acc[cb], 0,0,0);
        }
      }
    }
    // ---- epilogue ----
    float inv[4];
    #pragma unroll
    for (int r=0;r<4;r++) inv[r] = 1.0f / lsum[r];
    #pragma unroll
    for (int cb=0;cb<16;cb++)
      #pragma unroll
      for (int r=0;r<4;r++){
        int qrow = q0 + R + g*4 + r;
        Og[((long)z*S_ + qrow)*512 + Dh + cb*16 + c16] = __float2bfloat16(acc[cb][r]*inv[r]);
      }
  }
}

// ---------------- launch ----------------------------------------------------
extern "C" void kernel_launch(void* const* d_in, const int* in_sizes, int n_in,
                              void* d_out, int out_size, void* d_ws, size_t ws_size,
                              hipStream_t stream)
{
  const float* hidden = (const float*)d_in[0];
  const float* qn_w   = (const float*)d_in[1];
  const float* qpe_w  = (const float*)d_in[2];
  const float* kva_w  = (const float*)d_in[3];
  const float* ln_w   = (const float*)d_in[4];
  const float* kb_w   = (const float*)d_in[5];
  const float* vb_w   = (const float*)d_in[6];
  const float* o_w    = (const float*)d_in[7];
  const int*   pos    = (const int*)d_in[8];
  float* out = (float*)d_out;
  char* ws = (char*)d_ws;

  float* cosT  = (float*)(ws);                 //    262144
  float* sinT  = (float*)(ws + 262144);        //    262144
  bf16*  ckvb  = (bf16*) (ws + 524288);        //  4718592  (B,S,576) [dead after build_k]
  bf16*  vbb   = (bf16*) (ws + 524288);        //  2097152  alias in ckvb (cast after build_k)
  bf16*  Qb    = (bf16*) (ws + 5242880);       // 75497472  (B*H,S,576) [dead after attn]
  bf16*  ob    = (bf16*) (ws + 5242880);       //  8388608  alias in Qb (cast after attn)
  bf16*  Kb    = (bf16*) (ws + 80740352);      //  4718592  (B,S,576)
  bf16*  outl  = (bf16*) (ws + 85458944);      // 67108864  (B*H,S,512)
  bf16*  qnopeb= (bf16*) (ws + 85458944);      // 16777216  alias in outl (dead pre-attn)
  bf16*  qpeb  = (bf16*) (ws + 102236160);     //  8388608  alias
  bf16*  kbT   = (bf16*) (ws + 110624768);     //  2097152  alias
  bf16*  hb    = (bf16*) (ws + 112721920);     // 16777216  alias
  bf16*  qnb   = (bf16*) (ws + 129499136);     //  8388608  alias
  bf16*  qpw   = (bf16*) (ws + 137887744);     //  4194304  alias
  bf16*  kvab  = (bf16*) (ws + 142082048);     //  2359296  alias (ends 144441344)
  bf16*  voutb = (bf16*) (ws + 152567808);     // 16777216  (B,S,2048)
  bf16*  Kd    = (bf16*) (ws + 169345024);     //  4194304  (B,512,S) ends 173539328

  static_assert(sizeof(v8bf) == 16, "v8bf must be 16B");
  hipFuncSetAttribute((const void*)attn_mfma_kernel,
                      hipFuncAttributeMaxDynamicSharedMemorySize, SMEM_BYTES);

  cossin_kernel<<<256, 256, 0, stream>>>(pos, cosT, sinT);

  // pre-casts to bf16
  castf2b_kernel<<<4096, 256, 0, stream>>>(hidden, hb, 1048576);
  castf2b_kernel<<<2048, 256, 0, stream>>>(qn_w,  qnb, 524288);
  castf2b_kernel<<<1024, 256, 0, stream>>>(qpe_w, qpw, 262144);
  castf2b_kernel<<< 576, 256, 0, stream>>>(kva_w, kvab, 147456);

  // fused projections: q_nope, q_pe, ckv  (A = hb, K=2048)
  proj3_kernel<<<dim3(29,32,1),256,0,stream>>>(hb, qnb, qpw, kvab,
                                               qnopeb, qpeb, ckvb);

  kbT_kernel<<<dim3(8,2,16), 256, 0, stream>>>(kb_w, kbT);
  build_k_kernel<<<4096, 256, 0, stream>>>(ckvb, ln_w, cosT, sinT, Kb);
  castf2b_kernel<<<512, 256, 0, stream>>>(vb_w, vbb, 131072);   // into dead ckvb
  tposeV_kernel<<<dim3(8,32,2), 256, 0, stream>>>(Kb, Kd);
  rope_q_kernel<<<8192, 256, 0, stream>>>(qpeb, cosT, sinT, Qb);

  // q_lat = q_nope @ kbT[n]^T  (per (b,n): 2048x512, K=128), *SCALE -> Q[:, :512]
  gemm2_kernel<bf16><<<dim3(4,16,32),256,0,stream>>>(
      qnopeb,2048, 16,(long)S_*2048,128,  kbT,128, 16,0,65536,
      Qb,576, 1,(long)S_*576,0,  512,128, SCALE_F);

  attn_mfma_kernel<<<dim3(512), 512, SMEM_BYTES, stream>>>(Qb, Kb, Kd, outl);

  castf2b_kernel<<<2048, 256, 0, stream>>>(o_w, ob, 524288);    // into dead Qb

  // v_out = out_lat @ vbb[n]^T  (per (b,n): 2048x128, K=512) -> (B,S,H*DV)
  gemm2_kernel<bf16><<<dim3(1,16,32),256,0,stream>>>(
      outl,512, 1,(long)S_*512,0,  vbb,512, 16,0,65536,
      voutb,2048, 16,(long)S_*2048,128,  128,512, 1.f);

  // out = v_out @ ob^T  (4096 x 2048)
  gemm2_kernel<float><<<dim3(16,32,1),256,0,stream>>>(
      voutb,2048, 1,0,0,  ob,2048, 1,0,0,  out,2048, 1,0,0,  2048,2048, 1.f);
}

// Round 13
// 550.889 us; speedup vs baseline: 2.5593x; 1.0918x over previous
//
#include <hip/hip_runtime.h>
#include <hip/hip_bf16.h>

// DeepSeek-V2 MLA prefill, B=2 S=2048 HID=2048 H=16 DN=128 DR=64 KVR=512 DV=128
// Round 13: swapped-QK (mfma(kf,qf)) -> q-row lane-resident; all-lane softmax,
// in-register P repack (8 shfl), 2 barriers/tile, no P/alps LDS. Staging cadence
// byte-identical to R12.

typedef __hip_bfloat16 bf16;
typedef __bf16 v8bf __attribute__((ext_vector_type(8)));
typedef float  v4f  __attribute__((ext_vector_type(4)));
typedef unsigned int v4u __attribute__((ext_vector_type(4)));

#define S_    2048
#define SCALE_F 0.07216878364870322f   // (128+64)^-0.5

__device__ __forceinline__ void st1(float* p, float v){ *p = v; }
__device__ __forceinline__ void st1(bf16* p, float v){ *p = __float2bfloat16(v); }
__device__ __forceinline__ unsigned short bfb(float x){
  return __builtin_bit_cast(unsigned short, __float2bfloat16(x));
}
__device__ __forceinline__ unsigned pk2(float a, float b){
  return (unsigned)bfb(a) | ((unsigned)bfb(b) << 16);
}

// async global->LDS 16B (linear LDS dest = wave-uniform base + lane*16)
typedef const void __attribute__((address_space(1)))* gas_t;
typedef void __attribute__((address_space(3)))* las_t;
__device__ __forceinline__ void g2l16(const void* g, void* l){
  __builtin_amdgcn_global_load_lds((gas_t)g, (las_t)l, 16, 0, 0);
}

// ---------------- cos/sin table: (S,32) each ----------------
__global__ void cossin_kernel(const int* __restrict__ pos, float* __restrict__ cosT,
                              float* __restrict__ sinT){
  int idx = blockIdx.x*256 + threadIdx.x;       // S*32 = 65536
  int i = idx & 31, s = idx >> 5;
  float t = (float)pos[s];
  float freq = t * powf(10000.0f, -(float)i/32.0f);
  cosT[idx] = cosf(freq);
  sinT[idx] = sinf(freq);
}

// ---------------- f32 -> bf16 cast (vector x8) ------------------------------
__global__ void castf2b_kernel(const float* __restrict__ src, bf16* __restrict__ dst, int n8){
  int i = blockIdx.x*256 + threadIdx.x;
  if (i >= n8) return;
  const float4* s = (const float4*)src;
  float4 a = s[2*i], b = s[2*i+1];
  uint4 o; o.x = pk2(a.x,a.y); o.y = pk2(a.z,a.w); o.z = pk2(b.x,b.y); o.w = pk2(b.z,b.w);
  ((uint4*)dst)[i] = o;
}

// ---------------- MFMA GEMM (m97-style): C = A @ W^T ------------------------
// 128x128 tile, BK=32, dbuf LDS via global_load_lds(16B). A,W bf16 row-major.
template<typename TC>
__global__ __launch_bounds__(256) void gemm2_kernel(
    const bf16* __restrict__ A, int lda, int aDiv, long aS1, long aS2,
    const bf16* __restrict__ W, int ldw, int wDiv, long wS1, long wS2,
    TC* __restrict__ C, int ldc, int cDiv, long cS1, long cS2,
    int N, int K, float alpha)
{
  int z = blockIdx.z;
  A += (long)(z/aDiv)*aS1 + (long)(z%aDiv)*aS2;
  W += (long)(z/wDiv)*wS1 + (long)(z%wDiv)*wS2;
  C += (long)(z/cDiv)*cS1 + (long)(z%cDiv)*cS2;
  __shared__ bf16 As[2][4096];
  __shared__ bf16 Ws[2][4096];
  const int tid = threadIdx.x;
  const int w = tid>>6, l = tid&63, g = l>>4, c16 = l&15;
  const int wr = (w>>1)*64, wc = (w&1)*64;
  const int row0 = blockIdx.y*128, col0 = blockIdx.x*128;

  const long aO1 = (long)(row0 + (tid>>2))*lda + (tid&3)*8;
  const long aO2 = (long)(row0 + 64 + (tid>>2))*lda + (tid&3)*8;
  int wr1 = col0 + (tid>>2);      if (wr1 > N-1) wr1 = N-1;
  int wr2 = col0 + 64 + (tid>>2); if (wr2 > N-1) wr2 = N-1;
  const long wO1 = (long)wr1*ldw + (tid&3)*8;
  const long wO2 = (long)wr2*ldw + (tid&3)*8;

  v4f acc[4][4];
  #pragma unroll
  for (int i=0;i<4;i++)
    #pragma unroll
    for (int j=0;j<4;j++) acc[i][j] = (v4f){0.f,0.f,0.f,0.f};

  auto STAGE = [&](int k0, int bsel){
    g2l16(A + aO1 + k0, &As[bsel][tid*8]);
    g2l16(A + aO2 + k0, &As[bsel][2048 + tid*8]);
    g2l16(W + wO1 + k0, &Ws[bsel][tid*8]);
    g2l16(W + wO2 + k0, &Ws[bsel][2048 + tid*8]);
  };
  STAGE(0, 0);
  __syncthreads();
  const int nk = K >> 5;
  for (int t=0; t<nk; ++t){
    const int cur = t & 1;
    if (t+1 < nk) STAGE((t+1)*32, cur^1);
    v8bf af[4], bw[4];
    #pragma unroll
    for (int mi=0;mi<4;mi++) af[mi] = *(const v8bf*)&As[cur][(wr+mi*16+c16)*32 + g*8];
    #pragma unroll
    for (int ni=0;ni<4;ni++) bw[ni] = *(const v8bf*)&Ws[cur][(wc+ni*16+c16)*32 + g*8];
    #pragma unroll
    for (int mi=0;mi<4;mi++)
      #pragma unroll
      for (int ni=0;ni<4;ni++)
        acc[mi][ni] = __builtin_amdgcn_mfma_f32_16x16x32_bf16(af[mi], bw[ni], acc[mi][ni], 0,0,0);
    __syncthreads();
  }
  #pragma unroll
  for (int mi=0;mi<4;mi++)
    #pragma unroll
    for (int ni=0;ni<4;ni++)
      #pragma unroll
      for (int r=0;r<4;r++){
        int row = row0 + wr + mi*16 + g*4 + r;
        int col = col0 + wc + ni*16 + c16;
        if (col < N) st1(C + (long)row*ldc + col, acc[mi][ni][r]*alpha);
      }
}

// ---------------- fused projections: {q_nope, q_pe, ckv} = hb @ W^T ----------
__global__ __launch_bounds__(256) void proj3_kernel(
    const bf16* __restrict__ A,
    const bf16* __restrict__ Wq, const bf16* __restrict__ Wp, const bf16* __restrict__ Wc,
    bf16* __restrict__ Cq, bf16* __restrict__ Cp, bf16* __restrict__ Cc)
{
  const int bx = blockIdx.x;
  const bf16* W; bf16* C; int ldc, N, col0;
  if (bx < 16){ W = Wq; C = Cq; ldc = 2048; N = 2048; col0 = bx*128; }
  else if (bx < 24){ W = Wp; C = Cp; ldc = 1024; N = 1024; col0 = (bx-16)*128; }
  else { W = Wc; C = Cc; ldc = 576; N = 576; col0 = (bx-24)*128; }
  __shared__ bf16 As[2][4096];
  __shared__ bf16 Ws[2][4096];
  const int tid = threadIdx.x;
  const int w = tid>>6, l = tid&63, g = l>>4, c16 = l&15;
  const int wr = (w>>1)*64, wc = (w&1)*64;
  const int row0 = blockIdx.y*128;

  const long aO1 = (long)(row0 + (tid>>2))*2048 + (tid&3)*8;
  const long aO2 = (long)(row0 + 64 + (tid>>2))*2048 + (tid&3)*8;
  int wr1 = col0 + (tid>>2);      if (wr1 > N-1) wr1 = N-1;
  int wr2 = col0 + 64 + (tid>>2); if (wr2 > N-1) wr2 = N-1;
  const long wO1 = (long)wr1*2048 + (tid&3)*8;
  const long wO2 = (long)wr2*2048 + (tid&3)*8;

  v4f acc[4][4];
  #pragma unroll
  for (int i=0;i<4;i++)
    #pragma unroll
    for (int j=0;j<4;j++) acc[i][j] = (v4f){0.f,0.f,0.f,0.f};

  auto STAGE = [&](int k0, int bsel){
    g2l16(A + aO1 + k0, &As[bsel][tid*8]);
    g2l16(A + aO2 + k0, &As[bsel][2048 + tid*8]);
    g2l16(W + wO1 + k0, &Ws[bsel][tid*8]);
    g2l16(W + wO2 + k0, &Ws[bsel][2048 + tid*8]);
  };
  STAGE(0, 0);
  __syncthreads();
  for (int t=0; t<64; ++t){
    const int cur = t & 1;
    if (t+1 < 64) STAGE((t+1)*32, cur^1);
    v8bf af[4], bw[4];
    #pragma unroll
    for (int mi=0;mi<4;mi++) af[mi] = *(const v8bf*)&As[cur][(wr+mi*16+c16)*32 + g*8];
    #pragma unroll
    for (int ni=0;ni<4;ni++) bw[ni] = *(const v8bf*)&Ws[cur][(wc+ni*16+c16)*32 + g*8];
    #pragma unroll
    for (int mi=0;mi<4;mi++)
      #pragma unroll
      for (int ni=0;ni<4;ni++)
        acc[mi][ni] = __builtin_amdgcn_mfma_f32_16x16x32_bf16(af[mi], bw[ni], acc[mi][ni], 0,0,0);
    __syncthreads();
  }
  #pragma unroll
  for (int mi=0;mi<4;mi++)
    #pragma unroll
    for (int ni=0;ni<4;ni++)
      #pragma unroll
      for (int r=0;r<4;r++){
        int row = row0 + wr + mi*16 + g*4 + r;
        int col = col0 + wc + ni*16 + c16;
        if (col < N) C[(long)row*ldc + col] = __float2bfloat16(acc[mi][ni][r]);
      }
}

// ---------------- k_b cast+transpose: (16,128,512)f32 -> (16,512,128)bf16 ----
__global__ __launch_bounds__(256) void kbT_kernel(const float* __restrict__ kb,
                                                  bf16* __restrict__ kbT){
  __shared__ bf16 t[64][65];
  int h = blockIdx.z, c0 = blockIdx.x*64, d0 = blockIdx.y*64;
  const float* src = kb + ((long)h*128 + d0)*512 + c0;
  #pragma unroll
  for (int i=0;i<16;i++){
    int idx = i*256 + threadIdx.x;
    int dl = idx>>6, cl = idx&63;
    t[dl][cl] = __float2bfloat16(src[(long)dl*512 + cl]);
  }
  __syncthreads();
  bf16* dst = kbT + ((long)h*512 + c0)*128 + d0;
  #pragma unroll
  for (int i=0;i<16;i++){
    int idx = i*256 + threadIdx.x;
    int cl = idx>>6, dl = idx&63;
    dst[(long)cl*128 + dl] = t[dl][cl];
  }
}

// ---------------- V transpose: Kb(B,S,576)[:,:512] -> Kd(B,512,S) bf16 ------
__global__ __launch_bounds__(256) void tposeV_kernel(const bf16* __restrict__ Kb,
                                                     bf16* __restrict__ Kd){
  __shared__ bf16 t[64][65];
  int b = blockIdx.z, s0 = blockIdx.y*64, d0 = blockIdx.x*64;
  const bf16* src = Kb + ((long)(b*S_ + s0))*576 + d0;
  #pragma unroll
  for (int i=0;i<16;i++){
    int idx = i*256 + threadIdx.x;
    int sl = idx>>6, dl = idx&63;
    t[sl][dl] = src[(long)sl*576 + dl];
  }
  __syncthreads();
  bf16* dst = Kd + ((long)(b*512 + d0))*S_ + s0;
  #pragma unroll
  for (int i=0;i<16;i++){
    int idx = i*256 + threadIdx.x;
    int dl = idx>>6, sl = idx&63;
    dst[(long)dl*S_ + sl] = t[sl][dl];
  }
}

// ---------------- RMSNorm(ckv) + RoPE(k_pe) -> K bf16 (B,S,576) -------------
__global__ __launch_bounds__(256) void build_k_kernel(
    const bf16* __restrict__ ckv_kpe, const float* __restrict__ ln_w,
    const float* __restrict__ cosT, const float* __restrict__ sinT,
    bf16* __restrict__ Kb)
{
  int row = blockIdx.x;            // b*S + s
  int s = row & (S_-1);
  int tid = threadIdx.x;
  const bf16* src = ckv_kpe + (long)row*576;
  float x0 = __bfloat162float(src[tid*2]), x1 = __bfloat162float(src[tid*2+1]);
  float ss = x0*x0 + x1*x1;
  #pragma unroll
  for (int o=32;o>=1;o>>=1) ss += __shfl_xor(ss, o, 64);
  __shared__ float wss[4];
  int wid = tid>>6, lane = tid&63;
  if (lane==0) wss[wid] = ss;
  __syncthreads();
  float tot = wss[0]+wss[1]+wss[2]+wss[3];
  float rs = rsqrtf(tot*(1.0f/512.0f) + 1e-6f);
  bf16* dst = Kb + (long)row*576;
  dst[tid*2]   = __float2bfloat16(x0*rs*ln_w[tid*2]);
  dst[tid*2+1] = __float2bfloat16(x1*rs*ln_w[tid*2+1]);
  if (tid < 32) {
    float p0 = __bfloat162float(src[512 + tid*2]);
    float p1 = __bfloat162float(src[512 + tid*2 + 1]);
    float c = cosT[s*32+tid], sn = sinT[s*32+tid];
    dst[512+tid] = __float2bfloat16(p0*c - p1*sn);
    dst[544+tid] = __float2bfloat16(p1*c + p0*sn);
  }
}

// ---------------- RoPE(q_pe)*SCALE -> Q cols 512..575 -----------------------
__global__ void rope_q_kernel(const bf16* __restrict__ qpe,
                              const float* __restrict__ cosT, const float* __restrict__ sinT,
                              bf16* __restrict__ Qb)
{
  int idx = blockIdx.x*256 + threadIdx.x;   // B*H*S*32 = 2097152
  int i = idx & 31;
  int s = (idx >> 5) & (S_-1);
  int z = idx >> 16;                        // b*16+n
  int b = z >> 4, n = z & 15;
  long base = ((long)(b*S_+s))*1024 + n*64 + 2*i;
  float x0 = __bfloat162float(qpe[base]), x1 = __bfloat162float(qpe[base+1]);
  float c = cosT[s*32+i], sn = sinT[s*32+i];
  bf16* dst = Qb + ((long)z*S_ + s)*576;
  dst[512+i] = __float2bfloat16((x0*c - x1*sn)*SCALE_F);
  dst[544+i] = __float2bfloat16((x1*c + x0*sn)*SCALE_F);
}

// ---------------- MFMA flash attention (round 13) ----------------------------
// Swapped QK: q-row lane-resident; in-register softmax + P repack; 2 bar/tile.
#define K0_OFF 0
#define K1_OFF 36864
#define V0_OFF 73728
#define V1_OFF 106496
#define SX_OFF 139264     // 4 rg x 2 dh x 16 row x 16 perm x 8B = 16384
#define SMEM_BYTES 155648

__global__ __launch_bounds__(512, 2) void attn_mfma_kernel(
    const bf16* __restrict__ Qg, const bf16* __restrict__ Kg,
    const bf16* __restrict__ Vdg, bf16* __restrict__ Og)
{
  extern __shared__ char smem[];
  const int tid = threadIdx.x;
  const int w   = tid >> 6;
  const int l   = tid & 63;
  const int g   = l >> 4;
  const int c16 = l & 15;
  const int rg  = w & 3;
  const int dh  = w >> 2;
  const int R   = rg * 16;          // row block within Q tile
  const int Dh  = dh * 256;         // O d half (PV)
  const int DQb = dh * 576;         // QK d-half byte offset (288 elems)
  char* SXw = smem + SX_OFF + rg*4096 + dh*2048;
  char* SXr = smem + SX_OFF + rg*4096 + (1-dh)*2048;

  // XCD-aware mapping: each XCD works on one batch b
  const int lin = blockIdx.x;       // 0..511
  const int k8 = lin & 7;
  const int b  = k8 >> 2;
  const int u  = (lin >> 3)*4 + (k8 & 3);   // 0..255
  const int n  = u & 15;
  const int pr = u >> 4;                    // 0..15 (q-tile pair id)
  const int z  = b*16 + n;

  const char* kb0 = (const char*)Kg  + (long)b*S_*1152;
  const char* vd0 = (const char*)Vdg + (long)b*512*S_*2;

  // ---- hoisted staging offsets (tid-only, loop-invariant) ----
  int kOffG[5], kOffL[5], vOffG[4], vOffL[4];
  #pragma unroll
  for (int it=0; it<4; it++){
    int c = it*512 + tid;
    int kcol = c/72, j = c - kcol*72;
    kOffG[it] = kcol*1152 + ((j ^ (kcol&7))<<4);
    kOffL[it] = c*16;
  }
  {
    int c = 2048 + tid;
    int kcol = c/72, j = c - kcol*72;
    kOffG[4] = kcol*1152 + ((j ^ (kcol&7))<<4);
    kOffL[4] = c*16;
  }
  #pragma unroll
  for (int it=0; it<4; it++){
    int c = it*512 + tid;
    int s = c>>3, uu = (c&7) ^ (s&7);
    int d = 2*s + (uu>>2), j = uu&3;
    vOffG[it] = d*(S_*2) + j*16;
    vOffL[it] = c*16;
  }

  auto STAGE = [&](int tt, char* kd, char* vd){
    const char* ksrc = kb0 + (long)tt*36864;
    #pragma unroll
    for (int it=0; it<4; it++) g2l16(ksrc + kOffG[it], kd + kOffL[it]);
    if (tid < 256) g2l16(ksrc + kOffG[4], kd + kOffL[4]);
    const char* vsrc = vd0 + (long)tt*64;
    #pragma unroll
    for (int it=0; it<4; it++) g2l16(vsrc + vOffG[it], vd + vOffL[it]);
  };

  // SX lane offsets (hoisted)
  int sxo[4];
  #pragma unroll
  for (int r=0;r<4;r++) sxo[r] = c16*128 + ((((g*4+r) + c16) & 15)<<3);
  const int srcA = ((2*g)&3)*16 + c16;
  const int srcB = ((2*g+1)&3)*16 + c16;
  const bool hiG = (g >= 2);

  for (int ph = 0; ph < 2; ++ph){
    const int qt = ph ? (31 - pr) : pr;
    const int q0 = qt * 64;

    // Q fragments (d-half): rows q0+R+c16, d = dh*288 + kk*32 + g*8
    v8bf qf[9];
    {
      const char* qgb = (const char*)Qg + ((long)z*S_ + q0 + R + c16)*1152 + DQb;
      #pragma unroll
      for (int kk=0;kk<9;kk++) qf[kk] = *(const v8bf*)(qgb + kk*64 + g*16);
    }
    v4f acc[16];
    #pragma unroll
    for (int i=0;i<16;i++) acc[i] = (v4f){0.f,0.f,0.f,0.f};
    float mL = -1e30f;     // running max for lane-row c16
    float lsumL = 0.f;

    const int ntile = 2*qt + 2;
    __syncthreads();                       // prior phase LDS readers done
    STAGE(0, smem + K0_OFF, smem + V0_OFF);

    for (int t = 0; t < ntile; ++t){
      asm volatile("s_waitcnt vmcnt(0)" ::: "memory");
      __syncthreads();                     // buf[t&1] staged & visible
      char* kB = smem + ((t&1) ? K1_OFF : K0_OFF);
      char* vB = smem + ((t&1) ? V1_OFF : V0_OFF);
      if (t+1 < ntile)
        STAGE(t+1, smem + (((t+1)&1) ? K1_OFF : K0_OFF),
                    smem + (((t+1)&1) ? V1_OFF : V0_OFF));

      // ---- swapped QK^T partial: lane holds S[q-row=c16][k=cb*16+g*4+r] ----
      v4f s0 = (v4f){0.f,0.f,0.f,0.f}, s1 = (v4f){0.f,0.f,0.f,0.f};
      #pragma unroll
      for (int kk=0;kk<9;kk++){
        int j = dh*36 + kk*4 + g;
        v8bf kf0 = *(const v8bf*)(kB + c16*1152      + ((j ^ (c16&7))<<4));
        v8bf kf1 = *(const v8bf*)(kB + (16+c16)*1152 + ((j ^ (c16&7))<<4));
        s0 = __builtin_amdgcn_mfma_f32_16x16x32_bf16(kf0, qf[kk], s0, 0,0,0);
        s1 = __builtin_amdgcn_mfma_f32_16x16x32_bf16(kf1, qf[kk], s1, 0,0,0);
      }
      // ---- pair exchange of d-half partials (float2 per r) ----
      #pragma unroll
      for (int r=0;r<4;r++)
        *(float2*)(SXw + sxo[r]) = make_float2(s0[r], s1[r]);
      asm volatile("s_waitcnt lgkmcnt(0)" ::: "memory");
      __builtin_amdgcn_s_barrier();
      __builtin_amdgcn_sched_barrier(0);
      #pragma unroll
      for (int r=0;r<4;r++){
        float2 o = *(const float2*)(SXr + sxo[r]);
        s0[r] += o.x; s1[r] += o.y;
      }
      // ---- causal mask ----
      if (t >= ntile-2){
        int kt0 = t*32;
        int qrow = q0 + R + c16;
        #pragma unroll
        for (int r=0;r<4;r++){
          if (kt0 + g*4 + r > qrow)      s0[r] = -1e30f;
          if (kt0 + 16 + g*4 + r > qrow) s1[r] = -1e30f;
        }
      }
      // ---- all-lane softmax (row = c16), defer-max THR=8 ----
      float pm = fmaxf(fmaxf(fmaxf(s0[0],s0[1]),fmaxf(s0[2],s0[3])),
                       fmaxf(fmaxf(s1[0],s1[1]),fmaxf(s1[2],s1[3])));
      pm = fmaxf(pm, __shfl_xor(pm, 16));
      pm = fmaxf(pm, __shfl_xor(pm, 32));
      float alv = 1.0f;
      if (pm > mL + 8.0f){ alv = __expf(mL - pm); mL = pm; }
      float p0[4], p1[4];
      float sv = 0.f;
      #pragma unroll
      for (int r=0;r<4;r++){
        p0[r] = __expf(s0[r] - mL);
        p1[r] = __expf(s1[r] - mL);
        sv += p0[r] + p1[r];
      }
      sv += __shfl_xor(sv, 16);
      sv += __shfl_xor(sv, 32);
      lsumL = lsumL*alv + sv;
      // ---- pack P + lane repack -> PV A-fragment ----
      unsigned u0 = pk2(p0[0],p0[1]), u1 = pk2(p0[2],p0[3]);
      unsigned u2 = pk2(p1[0],p1[1]), u3 = pk2(p1[2],p1[3]);
      unsigned a0 = __shfl(u0, srcA), a1 = __shfl(u1, srcA);
      unsigned a2 = __shfl(u2, srcA), a3 = __shfl(u3, srcA);
      unsigned b0 = __shfl(u0, srcB), b1 = __shfl(u1, srcB);
      unsigned b2 = __shfl(u2, srcB), b3 = __shfl(u3, srcB);
      v4u paw;
      paw.x = hiG ? a2 : a0;  paw.y = hiG ? a3 : a1;
      paw.z = hiG ? b2 : b0;  paw.w = hiG ? b3 : b1;
      v8bf pa = __builtin_bit_cast(v8bf, paw);
      // ---- rescale (rare under defer-max) ----
      if (!__all((int)(alv == 1.0f))){
        float alr[4];
        #pragma unroll
        for (int r=0;r<4;r++) alr[r] = __shfl(alv, (l & 48) | (g*4+r));
        #pragma unroll
        for (int cb=0;cb<16;cb++)
          #pragma unroll
          for (int r=0;r<4;r++) acc[cb][r] *= alr[r];
      }
      // ---- PV: acc[row = R+g*4+r][d = Dh+cb*16+c16] ----
      #pragma unroll
      for (int cb=0;cb<16;cb++){
        int d = Dh + cb*16 + c16;
        int vu = ((((d&1)<<2)) | g) ^ ((d>>1)&7);
        v8bf vf = *(const v8bf*)(vB + (d>>1)*128 + (vu<<4));
        acc[cb] = __builtin_amdgcn_mfma_f32_16x16x32_bf16(pa, vf, acc[cb], 0,0,0);
      }
    }
    // ---- epilogue ----
    float invL = 1.0f / lsumL;
    float invr[4];
    #pragma unroll
    for (int r=0;r<4;r++) invr[r] = __shfl(invL, (l & 48) | (g*4+r));
    #pragma unroll
    for (int cb=0;cb<16;cb++)
      #pragma unroll
      for (int r=0;r<4;r++){
        int qrow = q0 + R + g*4 + r;
        Og[((long)z*S_ + qrow)*512 + Dh + cb*16 + c16] = __float2bfloat16(acc[cb][r]*invr[r]);
      }
  }
}

// ---------------- launch ----------------------------------------------------
extern "C" void kernel_launch(void* const* d_in, const int* in_sizes, int n_in,
                              void* d_out, int out_size, void* d_ws, size_t ws_size,
                              hipStream_t stream)
{
  const float* hidden = (const float*)d_in[0];
  const float* qn_w   = (const float*)d_in[1];
  const float* qpe_w  = (const float*)d_in[2];
  const float* kva_w  = (const float*)d_in[3];
  const float* ln_w   = (const float*)d_in[4];
  const float* kb_w   = (const float*)d_in[5];
  const float* vb_w   = (const float*)d_in[6];
  const float* o_w    = (const float*)d_in[7];
  const int*   pos    = (const int*)d_in[8];
  float* out = (float*)d_out;
  char* ws = (char*)d_ws;

  float* cosT  = (float*)(ws);                 //    262144
  float* sinT  = (float*)(ws + 262144);        //    262144
  bf16*  ckvb  = (bf16*) (ws + 524288);        //  4718592  (B,S,576) [dead after build_k]
  bf16*  vbb   = (bf16*) (ws + 524288);        //  2097152  alias in ckvb (cast after build_k)
  bf16*  Qb    = (bf16*) (ws + 5242880);       // 75497472  (B*H,S,576) [dead after attn]
  bf16*  ob    = (bf16*) (ws + 5242880);       //  8388608  alias in Qb (cast after attn)
  bf16*  Kb    = (bf16*) (ws + 80740352);      //  4718592  (B,S,576)
  bf16*  outl  = (bf16*) (ws + 85458944);      // 67108864  (B*H,S,512)
  bf16*  qnopeb= (bf16*) (ws + 85458944);      // 16777216  alias in outl (dead pre-attn)
  bf16*  qpeb  = (bf16*) (ws + 102236160);     //  8388608  alias
  bf16*  kbT   = (bf16*) (ws + 110624768);     //  2097152  alias
  bf16*  hb    = (bf16*) (ws + 112721920);     // 16777216  alias
  bf16*  qnb   = (bf16*) (ws + 129499136);     //  8388608  alias
  bf16*  qpw   = (bf16*) (ws + 137887744);     //  4194304  alias
  bf16*  kvab  = (bf16*) (ws + 142082048);     //  2359296  alias (ends 144441344)
  bf16*  voutb = (bf16*) (ws + 152567808);     // 16777216  (B,S,2048)
  bf16*  Kd    = (bf16*) (ws + 169345024);     //  4194304  (B,512,S) ends 173539328

  static_assert(sizeof(v8bf) == 16, "v8bf must be 16B");
  hipFuncSetAttribute((const void*)attn_mfma_kernel,
                      hipFuncAttributeMaxDynamicSharedMemorySize, SMEM_BYTES);

  cossin_kernel<<<256, 256, 0, stream>>>(pos, cosT, sinT);

  // pre-casts to bf16
  castf2b_kernel<<<4096, 256, 0, stream>>>(hidden, hb, 1048576);
  castf2b_kernel<<<2048, 256, 0, stream>>>(qn_w,  qnb, 524288);
  castf2b_kernel<<<1024, 256, 0, stream>>>(qpe_w, qpw, 262144);
  castf2b_kernel<<< 576, 256, 0, stream>>>(kva_w, kvab, 147456);

  // fused projections: q_nope, q_pe, ckv  (A = hb, K=2048)
  proj3_kernel<<<dim3(29,32,1),256,0,stream>>>(hb, qnb, qpw, kvab,
                                               qnopeb, qpeb, ckvb);

  kbT_kernel<<<dim3(8,2,16), 256, 0, stream>>>(kb_w, kbT);
  build_k_kernel<<<4096, 256, 0, stream>>>(ckvb, ln_w, cosT, sinT, Kb);
  castf2b_kernel<<<512, 256, 0, stream>>>(vb_w, vbb, 131072);   // into dead ckvb
  tposeV_kernel<<<dim3(8,32,2), 256, 0, stream>>>(Kb, Kd);
  rope_q_kernel<<<8192, 256, 0, stream>>>(qpeb, cosT, sinT, Qb);

  // q_lat = q_nope @ kbT[n]^T  (per (b,n): 2048x512, K=128), *SCALE -> Q[:, :512]
  gemm2_kernel<bf16><<<dim3(4,16,32),256,0,stream>>>(
      qnopeb,2048, 16,(long)S_*2048,128,  kbT,128, 16,0,65536,
      Qb,576, 1,(long)S_*576,0,  512,128, SCALE_F);

  attn_mfma_kernel<<<dim3(512), 512, SMEM_BYTES, stream>>>(Qb, Kb, Kd, outl);

  castf2b_kernel<<<2048, 256, 0, stream>>>(o_w, ob, 524288);    // into dead Qb

  // v_out = out_lat @ vbb[n]^T  (per (b,n): 2048x128, K=512) -> (B,S,H*DV)
  gemm2_kernel<bf16><<<dim3(1,16,32),256,0,stream>>>(
      outl,512, 1,(long)S_*512,0,  vbb,512, 16,0,65536,
      voutb,2048, 16,(long)S_*2048,128,  128,512, 1.f);

  // out = v_out @ ob^T  (4096 x 2048)
  gemm2_kernel<float><<<dim3(16,32,1),256,0,stream>>>(
      voutb,2048, 1,0,0,  ob,2048, 1,0,0,  out,2048, 1,0,0,  2048,2048, 1.f);
}

// Round 14
// 538.100 us; speedup vs baseline: 2.6202x; 1.0238x over previous
//
#include <hip/hip_runtime.h>
#include <hip/hip_bf16.h>

// DeepSeek-V2 MLA prefill, B=2 S=2048 HID=2048 H=16 DN=128 DR=64 KVR=512 DV=128
// Round 14: R13 + SX exchange as bank-uniform float4 (conflict fix, 4 fewer LDS
// ops/wave/tile) + 4 leading casts fused into one dispatch.

typedef __hip_bfloat16 bf16;
typedef __bf16 v8bf __attribute__((ext_vector_type(8)));
typedef float  v4f  __attribute__((ext_vector_type(4)));
typedef unsigned int v4u __attribute__((ext_vector_type(4)));

#define S_    2048
#define SCALE_F 0.07216878364870322f   // (128+64)^-0.5

__device__ __forceinline__ void st1(float* p, float v){ *p = v; }
__device__ __forceinline__ void st1(bf16* p, float v){ *p = __float2bfloat16(v); }
__device__ __forceinline__ unsigned short bfb(float x){
  return __builtin_bit_cast(unsigned short, __float2bfloat16(x));
}
__device__ __forceinline__ unsigned pk2(float a, float b){
  return (unsigned)bfb(a) | ((unsigned)bfb(b) << 16);
}

// async global->LDS 16B (linear LDS dest = wave-uniform base + lane*16)
typedef const void __attribute__((address_space(1)))* gas_t;
typedef void __attribute__((address_space(3)))* las_t;
__device__ __forceinline__ void g2l16(const void* g, void* l){
  __builtin_amdgcn_global_load_lds((gas_t)g, (las_t)l, 16, 0, 0);
}

// ---------------- cos/sin table: (S,32) each ----------------
__global__ void cossin_kernel(const int* __restrict__ pos, float* __restrict__ cosT,
                              float* __restrict__ sinT){
  int idx = blockIdx.x*256 + threadIdx.x;       // S*32 = 65536
  int i = idx & 31, s = idx >> 5;
  float t = (float)pos[s];
  float freq = t * powf(10000.0f, -(float)i/32.0f);
  cosT[idx] = cosf(freq);
  sinT[idx] = sinf(freq);
}

// ---------------- f32 -> bf16 cast (vector x8) ------------------------------
__global__ void castf2b_kernel(const float* __restrict__ src, bf16* __restrict__ dst, int n8){
  int i = blockIdx.x*256 + threadIdx.x;
  if (i >= n8) return;
  const float4* s = (const float4*)src;
  float4 a = s[2*i], b = s[2*i+1];
  uint4 o; o.x = pk2(a.x,a.y); o.y = pk2(a.z,a.w); o.z = pk2(b.x,b.y); o.w = pk2(b.z,b.w);
  ((uint4*)dst)[i] = o;
}

// ---------------- fused 4-input cast (hidden, qn_w, qpe_w, kva_w) -----------
__global__ void cast4_kernel(const float* __restrict__ a, bf16* __restrict__ da,
                             const float* __restrict__ b, bf16* __restrict__ db,
                             const float* __restrict__ c, bf16* __restrict__ dc,
                             const float* __restrict__ d, bf16* __restrict__ dd){
  int j = blockIdx.x*256 + threadIdx.x;
  const float* s; bf16* t;
  if (j < 1048576){ s=a; t=da; }
  else if ((j-=1048576) < 524288){ s=b; t=db; }
  else if ((j-=524288) < 262144){ s=c; t=dc; }
  else if ((j-=262144) < 147456){ s=d; t=dd; }
  else return;
  float4 x = ((const float4*)s)[2*j], y = ((const float4*)s)[2*j+1];
  uint4 o; o.x=pk2(x.x,x.y); o.y=pk2(x.z,x.w); o.z=pk2(y.x,y.y); o.w=pk2(y.z,y.w);
  ((uint4*)t)[j] = o;
}

// ---------------- MFMA GEMM (m97-style): C = A @ W^T ------------------------
template<typename TC>
__global__ __launch_bounds__(256) void gemm2_kernel(
    const bf16* __restrict__ A, int lda, int aDiv, long aS1, long aS2,
    const bf16* __restrict__ W, int ldw, int wDiv, long wS1, long wS2,
    TC* __restrict__ C, int ldc, int cDiv, long cS1, long cS2,
    int N, int K, float alpha)
{
  int z = blockIdx.z;
  A += (long)(z/aDiv)*aS1 + (long)(z%aDiv)*aS2;
  W += (long)(z/wDiv)*wS1 + (long)(z%wDiv)*wS2;
  C += (long)(z/cDiv)*cS1 + (long)(z%cDiv)*cS2;
  __shared__ bf16 As[2][4096];
  __shared__ bf16 Ws[2][4096];
  const int tid = threadIdx.x;
  const int w = tid>>6, l = tid&63, g = l>>4, c16 = l&15;
  const int wr = (w>>1)*64, wc = (w&1)*64;
  const int row0 = blockIdx.y*128, col0 = blockIdx.x*128;

  const long aO1 = (long)(row0 + (tid>>2))*lda + (tid&3)*8;
  const long aO2 = (long)(row0 + 64 + (tid>>2))*lda + (tid&3)*8;
  int wr1 = col0 + (tid>>2);      if (wr1 > N-1) wr1 = N-1;
  int wr2 = col0 + 64 + (tid>>2); if (wr2 > N-1) wr2 = N-1;
  const long wO1 = (long)wr1*ldw + (tid&3)*8;
  const long wO2 = (long)wr2*ldw + (tid&3)*8;

  v4f acc[4][4];
  #pragma unroll
  for (int i=0;i<4;i++)
    #pragma unroll
    for (int j=0;j<4;j++) acc[i][j] = (v4f){0.f,0.f,0.f,0.f};

  auto STAGE = [&](int k0, int bsel){
    g2l16(A + aO1 + k0, &As[bsel][tid*8]);
    g2l16(A + aO2 + k0, &As[bsel][2048 + tid*8]);
    g2l16(W + wO1 + k0, &Ws[bsel][tid*8]);
    g2l16(W + wO2 + k0, &Ws[bsel][2048 + tid*8]);
  };
  STAGE(0, 0);
  __syncthreads();
  const int nk = K >> 5;
  for (int t=0; t<nk; ++t){
    const int cur = t & 1;
    if (t+1 < nk) STAGE((t+1)*32, cur^1);
    v8bf af[4], bw[4];
    #pragma unroll
    for (int mi=0;mi<4;mi++) af[mi] = *(const v8bf*)&As[cur][(wr+mi*16+c16)*32 + g*8];
    #pragma unroll
    for (int ni=0;ni<4;ni++) bw[ni] = *(const v8bf*)&Ws[cur][(wc+ni*16+c16)*32 + g*8];
    #pragma unroll
    for (int mi=0;mi<4;mi++)
      #pragma unroll
      for (int ni=0;ni<4;ni++)
        acc[mi][ni] = __builtin_amdgcn_mfma_f32_16x16x32_bf16(af[mi], bw[ni], acc[mi][ni], 0,0,0);
    __syncthreads();
  }
  #pragma unroll
  for (int mi=0;mi<4;mi++)
    #pragma unroll
    for (int ni=0;ni<4;ni++)
      #pragma unroll
      for (int r=0;r<4;r++){
        int row = row0 + wr + mi*16 + g*4 + r;
        int col = col0 + wc + ni*16 + c16;
        if (col < N) st1(C + (long)row*ldc + col, acc[mi][ni][r]*alpha);
      }
}

// ---------------- fused projections: {q_nope, q_pe, ckv} = hb @ W^T ----------
__global__ __launch_bounds__(256) void proj3_kernel(
    const bf16* __restrict__ A,
    const bf16* __restrict__ Wq, const bf16* __restrict__ Wp, const bf16* __restrict__ Wc,
    bf16* __restrict__ Cq, bf16* __restrict__ Cp, bf16* __restrict__ Cc)
{
  const int bx = blockIdx.x;
  const bf16* W; bf16* C; int ldc, N, col0;
  if (bx < 16){ W = Wq; C = Cq; ldc = 2048; N = 2048; col0 = bx*128; }
  else if (bx < 24){ W = Wp; C = Cp; ldc = 1024; N = 1024; col0 = (bx-16)*128; }
  else { W = Wc; C = Cc; ldc = 576; N = 576; col0 = (bx-24)*128; }
  __shared__ bf16 As[2][4096];
  __shared__ bf16 Ws[2][4096];
  const int tid = threadIdx.x;
  const int w = tid>>6, l = tid&63, g = l>>4, c16 = l&15;
  const int wr = (w>>1)*64, wc = (w&1)*64;
  const int row0 = blockIdx.y*128;

  const long aO1 = (long)(row0 + (tid>>2))*2048 + (tid&3)*8;
  const long aO2 = (long)(row0 + 64 + (tid>>2))*2048 + (tid&3)*8;
  int wr1 = col0 + (tid>>2);      if (wr1 > N-1) wr1 = N-1;
  int wr2 = col0 + 64 + (tid>>2); if (wr2 > N-1) wr2 = N-1;
  const long wO1 = (long)wr1*2048 + (tid&3)*8;
  const long wO2 = (long)wr2*2048 + (tid&3)*8;

  v4f acc[4][4];
  #pragma unroll
  for (int i=0;i<4;i++)
    #pragma unroll
    for (int j=0;j<4;j++) acc[i][j] = (v4f){0.f,0.f,0.f,0.f};

  auto STAGE = [&](int k0, int bsel){
    g2l16(A + aO1 + k0, &As[bsel][tid*8]);
    g2l16(A + aO2 + k0, &As[bsel][2048 + tid*8]);
    g2l16(W + wO1 + k0, &Ws[bsel][tid*8]);
    g2l16(W + wO2 + k0, &Ws[bsel][2048 + tid*8]);
  };
  STAGE(0, 0);
  __syncthreads();
  for (int t=0; t<64; ++t){
    const int cur = t & 1;
    if (t+1 < 64) STAGE((t+1)*32, cur^1);
    v8bf af[4], bw[4];
    #pragma unroll
    for (int mi=0;mi<4;mi++) af[mi] = *(const v8bf*)&As[cur][(wr+mi*16+c16)*32 + g*8];
    #pragma unroll
    for (int ni=0;ni<4;ni++) bw[ni] = *(const v8bf*)&Ws[cur][(wc+ni*16+c16)*32 + g*8];
    #pragma unroll
    for (int mi=0;mi<4;mi++)
      #pragma unroll
      for (int ni=0;ni<4;ni++)
        acc[mi][ni] = __builtin_amdgcn_mfma_f32_16x16x32_bf16(af[mi], bw[ni], acc[mi][ni], 0,0,0);
    __syncthreads();
  }
  #pragma unroll
  for (int mi=0;mi<4;mi++)
    #pragma unroll
    for (int ni=0;ni<4;ni++)
      #pragma unroll
      for (int r=0;r<4;r++){
        int row = row0 + wr + mi*16 + g*4 + r;
        int col = col0 + wc + ni*16 + c16;
        if (col < N) C[(long)row*ldc + col] = __float2bfloat16(acc[mi][ni][r]);
      }
}

// ---------------- k_b cast+transpose: (16,128,512)f32 -> (16,512,128)bf16 ----
__global__ __launch_bounds__(256) void kbT_kernel(const float* __restrict__ kb,
                                                  bf16* __restrict__ kbT){
  __shared__ bf16 t[64][65];
  int h = blockIdx.z, c0 = blockIdx.x*64, d0 = blockIdx.y*64;
  const float* src = kb + ((long)h*128 + d0)*512 + c0;
  #pragma unroll
  for (int i=0;i<16;i++){
    int idx = i*256 + threadIdx.x;
    int dl = idx>>6, cl = idx&63;
    t[dl][cl] = __float2bfloat16(src[(long)dl*512 + cl]);
  }
  __syncthreads();
  bf16* dst = kbT + ((long)h*512 + c0)*128 + d0;
  #pragma unroll
  for (int i=0;i<16;i++){
    int idx = i*256 + threadIdx.x;
    int cl = idx>>6, dl = idx&63;
    dst[(long)cl*128 + dl] = t[dl][cl];
  }
}

// ---------------- V transpose: Kb(B,S,576)[:,:512] -> Kd(B,512,S) bf16 ------
__global__ __launch_bounds__(256) void tposeV_kernel(const bf16* __restrict__ Kb,
                                                     bf16* __restrict__ Kd){
  __shared__ bf16 t[64][65];
  int b = blockIdx.z, s0 = blockIdx.y*64, d0 = blockIdx.x*64;
  const bf16* src = Kb + ((long)(b*S_ + s0))*576 + d0;
  #pragma unroll
  for (int i=0;i<16;i++){
    int idx = i*256 + threadIdx.x;
    int sl = idx>>6, dl = idx&63;
    t[sl][dl] = src[(long)sl*576 + dl];
  }
  __syncthreads();
  bf16* dst = Kd + ((long)(b*512 + d0))*S_ + s0;
  #pragma unroll
  for (int i=0;i<16;i++){
    int idx = i*256 + threadIdx.x;
    int dl = idx>>6, sl = idx&63;
    dst[(long)dl*S_ + sl] = t[sl][dl];
  }
}

// ---------------- RMSNorm(ckv) + RoPE(k_pe) -> K bf16 (B,S,576) -------------
__global__ __launch_bounds__(256) void build_k_kernel(
    const bf16* __restrict__ ckv_kpe, const float* __restrict__ ln_w,
    const float* __restrict__ cosT, const float* __restrict__ sinT,
    bf16* __restrict__ Kb)
{
  int row = blockIdx.x;            // b*S + s
  int s = row & (S_-1);
  int tid = threadIdx.x;
  const bf16* src = ckv_kpe + (long)row*576;
  float x0 = __bfloat162float(src[tid*2]), x1 = __bfloat162float(src[tid*2+1]);
  float ss = x0*x0 + x1*x1;
  #pragma unroll
  for (int o=32;o>=1;o>>=1) ss += __shfl_xor(ss, o, 64);
  __shared__ float wss[4];
  int wid = tid>>6, lane = tid&63;
  if (lane==0) wss[wid] = ss;
  __syncthreads();
  float tot = wss[0]+wss[1]+wss[2]+wss[3];
  float rs = rsqrtf(tot*(1.0f/512.0f) + 1e-6f);
  bf16* dst = Kb + (long)row*576;
  dst[tid*2]   = __float2bfloat16(x0*rs*ln_w[tid*2]);
  dst[tid*2+1] = __float2bfloat16(x1*rs*ln_w[tid*2+1]);
  if (tid < 32) {
    float p0 = __bfloat162float(src[512 + tid*2]);
    float p1 = __bfloat162float(src[512 + tid*2 + 1]);
    float c = cosT[s*32+tid], sn = sinT[s*32+tid];
    dst[512+tid] = __float2bfloat16(p0*c - p1*sn);
    dst[544+tid] = __float2bfloat16(p1*c + p0*sn);
  }
}

// ---------------- RoPE(q_pe)*SCALE -> Q cols 512..575 -----------------------
__global__ void rope_q_kernel(const bf16* __restrict__ qpe,
                              const float* __restrict__ cosT, const float* __restrict__ sinT,
                              bf16* __restrict__ Qb)
{
  int idx = blockIdx.x*256 + threadIdx.x;   // B*H*S*32 = 2097152
  int i = idx & 31;
  int s = (idx >> 5) & (S_-1);
  int z = idx >> 16;                        // b*16+n
  int b = z >> 4, n = z & 15;
  long base = ((long)(b*S_+s))*1024 + n*64 + 2*i;
  float x0 = __bfloat162float(qpe[base]), x1 = __bfloat162float(qpe[base+1]);
  float c = cosT[s*32+i], sn = sinT[s*32+i];
  bf16* dst = Qb + ((long)z*S_ + s)*576;
  dst[512+i] = __float2bfloat16((x0*c - x1*sn)*SCALE_F);
  dst[544+i] = __float2bfloat16((x1*c + x0*sn)*SCALE_F);
}

// ---------------- MFMA flash attention (round 14) ----------------------------
// R13 + float4 SX exchange with bank-uniform slots.
#define K0_OFF 0
#define K1_OFF 36864
#define V0_OFF 73728
#define V1_OFF 106496
#define SX_OFF 139264     // 4 rg x 2 dh x 2048
#define SMEM_BYTES 155648

__global__ __launch_bounds__(512, 2) void attn_mfma_kernel(
    const bf16* __restrict__ Qg, const bf16* __restrict__ Kg,
    const bf16* __restrict__ Vdg, bf16* __restrict__ Og)
{
  extern __shared__ char smem[];
  const int tid = threadIdx.x;
  const int w   = tid >> 6;
  const int l   = tid & 63;
  const int g   = l >> 4;
  const int c16 = l & 15;
  const int rg  = w & 3;
  const int dh  = w >> 2;
  const int R   = rg * 16;          // row block within Q tile
  const int Dh  = dh * 256;         // O d half (PV)
  const int DQb = dh * 576;         // QK d-half byte offset (288 elems)
  char* SXw = smem + SX_OFF + rg*4096 + dh*2048;
  char* SXr = smem + SX_OFF + rg*4096 + (1-dh)*2048;

  // XCD-aware mapping: each XCD works on one batch b
  const int lin = blockIdx.x;       // 0..511
  const int k8 = lin & 7;
  const int b  = k8 >> 2;
  const int u  = (lin >> 3)*4 + (k8 & 3);   // 0..255
  const int n  = u & 15;
  const int pr = u >> 4;                    // 0..15 (q-tile pair id)
  const int z  = b*16 + n;

  const char* kb0 = (const char*)Kg  + (long)b*S_*1152;
  const char* vd0 = (const char*)Vdg + (long)b*512*S_*2;

  // ---- hoisted staging offsets (tid-only, loop-invariant) ----
  int kOffG[5], kOffL[5], vOffG[4], vOffL[4];
  #pragma unroll
  for (int it=0; it<4; it++){
    int c = it*512 + tid;
    int kcol = c/72, j = c - kcol*72;
    kOffG[it] = kcol*1152 + ((j ^ (kcol&7))<<4);
    kOffL[it] = c*16;
  }
  {
    int c = 2048 + tid;
    int kcol = c/72, j = c - kcol*72;
    kOffG[4] = kcol*1152 + ((j ^ (kcol&7))<<4);
    kOffL[4] = c*16;
  }
  #pragma unroll
  for (int it=0; it<4; it++){
    int c = it*512 + tid;
    int s = c>>3, uu = (c&7) ^ (s&7);
    int d = 2*s + (uu>>2), j = uu&3;
    vOffG[it] = d*(S_*2) + j*16;
    vOffL[it] = c*16;
  }

  auto STAGE = [&](int tt, char* kd, char* vd){
    const char* ksrc = kb0 + (long)tt*36864;
    #pragma unroll
    for (int it=0; it<4; it++) g2l16(ksrc + kOffG[it], kd + kOffL[it]);
    if (tid < 256) g2l16(ksrc + kOffG[4], kd + kOffL[4]);
    const char* vsrc = vd0 + (long)tt*64;
    #pragma unroll
    for (int it=0; it<4; it++) g2l16(vsrc + vOffG[it], vd + vOffL[it]);
  };

  // SX float4 slots (hoisted): p=0 -> r{0,1}, p=1 -> r{2,3}
  const int sxf0 = c16*128 + (((2*g + 0 + c16)&7)<<4);
  const int sxf1 = c16*128 + (((2*g + 1 + c16)&7)<<4);
  const int srcA = ((2*g)&3)*16 + c16;
  const int srcB = ((2*g+1)&3)*16 + c16;
  const bool hiG = (g >= 2);

  for (int ph = 0; ph < 2; ++ph){
    const int qt = ph ? (31 - pr) : pr;
    const int q0 = qt * 64;

    // Q fragments (d-half): rows q0+R+c16, d = dh*288 + kk*32 + g*8
    v8bf qf[9];
    {
      const char* qgb = (const char*)Qg + ((long)z*S_ + q0 + R + c16)*1152 + DQb;
      #pragma unroll
      for (int kk=0;kk<9;kk++) qf[kk] = *(const v8bf*)(qgb + kk*64 + g*16);
    }
    v4f acc[16];
    #pragma unroll
    for (int i=0;i<16;i++) acc[i] = (v4f){0.f,0.f,0.f,0.f};
    float mL = -1e30f;     // running max for lane-row c16
    float lsumL = 0.f;

    const int ntile = 2*qt + 2;
    __syncthreads();                       // prior phase LDS readers done
    STAGE(0, smem + K0_OFF, smem + V0_OFF);

    for (int t = 0; t < ntile; ++t){
      asm volatile("s_waitcnt vmcnt(0)" ::: "memory");
      __syncthreads();                     // buf[t&1] staged & visible
      char* kB = smem + ((t&1) ? K1_OFF : K0_OFF);
      char* vB = smem + ((t&1) ? V1_OFF : V0_OFF);
      if (t+1 < ntile)
        STAGE(t+1, smem + (((t+1)&1) ? K1_OFF : K0_OFF),
                    smem + (((t+1)&1) ? V1_OFF : V0_OFF));

      // ---- swapped QK^T partial: lane holds S[q-row=c16][k=cb*16+g*4+r] ----
      v4f s0 = (v4f){0.f,0.f,0.f,0.f}, s1 = (v4f){0.f,0.f,0.f,0.f};
      #pragma unroll
      for (int kk=0;kk<9;kk++){
        int j = dh*36 + kk*4 + g;
        v8bf kf0 = *(const v8bf*)(kB + c16*1152      + ((j ^ (c16&7))<<4));
        v8bf kf1 = *(const v8bf*)(kB + (16+c16)*1152 + ((j ^ (c16&7))<<4));
        s0 = __builtin_amdgcn_mfma_f32_16x16x32_bf16(kf0, qf[kk], s0, 0,0,0);
        s1 = __builtin_amdgcn_mfma_f32_16x16x32_bf16(kf1, qf[kk], s1, 0,0,0);
      }
      // ---- pair exchange of d-half partials (2x float4 per lane) ----
      *(float4*)(SXw + sxf0) = make_float4(s0[0], s0[1], s1[0], s1[1]);
      *(float4*)(SXw + sxf1) = make_float4(s0[2], s0[3], s1[2], s1[3]);
      asm volatile("s_waitcnt lgkmcnt(0)" ::: "memory");
      __builtin_amdgcn_s_barrier();
      __builtin_amdgcn_sched_barrier(0);
      {
        float4 o0 = *(const float4*)(SXr + sxf0);
        float4 o1 = *(const float4*)(SXr + sxf1);
        s0[0] += o0.x; s0[1] += o0.y; s1[0] += o0.z; s1[1] += o0.w;
        s0[2] += o1.x; s0[3] += o1.y; s1[2] += o1.z; s1[3] += o1.w;
      }
      // ---- causal mask ----
      if (t >= ntile-2){
        int kt0 = t*32;
        int qrow = q0 + R + c16;
        #pragma unroll
        for (int r=0;r<4;r++){
          if (kt0 + g*4 + r > qrow)      s0[r] = -1e30f;
          if (kt0 + 16 + g*4 + r > qrow) s1[r] = -1e30f;
        }
      }
      // ---- all-lane softmax (row = c16), defer-max THR=8 ----
      float pm = fmaxf(fmaxf(fmaxf(s0[0],s0[1]),fmaxf(s0[2],s0[3])),
                       fmaxf(fmaxf(s1[0],s1[1]),fmaxf(s1[2],s1[3])));
      pm = fmaxf(pm, __shfl_xor(pm, 16));
      pm = fmaxf(pm, __shfl_xor(pm, 32));
      float alv = 1.0f;
      if (pm > mL + 8.0f){ alv = __expf(mL - pm); mL = pm; }
      float p0[4], p1[4];
      float sv = 0.f;
      #pragma unroll
      for (int r=0;r<4;r++){
        p0[r] = __expf(s0[r] - mL);
        p1[r] = __expf(s1[r] - mL);
        sv += p0[r] + p1[r];
      }
      sv += __shfl_xor(sv, 16);
      sv += __shfl_xor(sv, 32);
      lsumL = lsumL*alv + sv;
      // ---- pack P + lane repack -> PV A-fragment ----
      unsigned u0 = pk2(p0[0],p0[1]), u1 = pk2(p0[2],p0[3]);
      unsigned u2 = pk2(p1[0],p1[1]), u3 = pk2(p1[2],p1[3]);
      unsigned a0 = __shfl(u0, srcA), a1 = __shfl(u1, srcA);
      unsigned a2 = __shfl(u2, srcA), a3 = __shfl(u3, srcA);
      unsigned b0 = __shfl(u0, srcB), b1 = __shfl(u1, srcB);
      unsigned b2 = __shfl(u2, srcB), b3 = __shfl(u3, srcB);
      v4u paw;
      paw.x = hiG ? a2 : a0;  paw.y = hiG ? a3 : a1;
      paw.z = hiG ? b2 : b0;  paw.w = hiG ? b3 : b1;
      v8bf pa = __builtin_bit_cast(v8bf, paw);
      // ---- rescale (rare under defer-max) ----
      if (!__all((int)(alv == 1.0f))){
        float alr[4];
        #pragma unroll
        for (int r=0;r<4;r++) alr[r] = __shfl(alv, (l & 48) | (g*4+r));
        #pragma unroll
        for (int cb=0;cb<16;cb++)
          #pragma unroll
          for (int r=0;r<4;r++) acc[cb][r] *= alr[r];
      }
      // ---- PV: acc[row = R+g*4+r][d = Dh+cb*16+c16] ----
      #pragma unroll
      for (int cb=0;cb<16;cb++){
        int d = Dh + cb*16 + c16;
        int vu = ((((d&1)<<2)) | g) ^ ((d>>1)&7);
        v8bf vf = *(const v8bf*)(vB + (d>>1)*128 + (vu<<4));
        acc[cb] = __builtin_amdgcn_mfma_f32_16x16x32_bf16(pa, vf, acc[cb], 0,0,0);
      }
    }
    // ---- epilogue ----
    float invL = 1.0f / lsumL;
    float invr[4];
    #pragma unroll
    for (int r=0;r<4;r++) invr[r] = __shfl(invL, (l & 48) | (g*4+r));
    #pragma unroll
    for (int cb=0;cb<16;cb++)
      #pragma unroll
      for (int r=0;r<4;r++){
        int qrow = q0 + R + g*4 + r;
        Og[((long)z*S_ + qrow)*512 + Dh + cb*16 + c16] = __float2bfloat16(acc[cb][r]*invr[r]);
      }
  }
}

// ---------------- launch ----------------------------------------------------
extern "C" void kernel_launch(void* const* d_in, const int* in_sizes, int n_in,
                              void* d_out, int out_size, void* d_ws, size_t ws_size,
                              hipStream_t stream)
{
  const float* hidden = (const float*)d_in[0];
  const float* qn_w   = (const float*)d_in[1];
  const float* qpe_w  = (const float*)d_in[2];
  const float* kva_w  = (const float*)d_in[3];
  const float* ln_w   = (const float*)d_in[4];
  const float* kb_w   = (const float*)d_in[5];
  const float* vb_w   = (const float*)d_in[6];
  const float* o_w    = (const float*)d_in[7];
  const int*   pos    = (const int*)d_in[8];
  float* out = (float*)d_out;
  char* ws = (char*)d_ws;

  float* cosT  = (float*)(ws);                 //    262144
  float* sinT  = (float*)(ws + 262144);        //    262144
  bf16*  ckvb  = (bf16*) (ws + 524288);        //  4718592  (B,S,576) [dead after build_k]
  bf16*  vbb   = (bf16*) (ws + 524288);        //  2097152  alias in ckvb (cast after build_k)
  bf16*  Qb    = (bf16*) (ws + 5242880);       // 75497472  (B*H,S,576) [dead after attn]
  bf16*  ob    = (bf16*) (ws + 5242880);       //  8388608  alias in Qb (cast after attn)
  bf16*  Kb    = (bf16*) (ws + 80740352);      //  4718592  (B,S,576)
  bf16*  outl  = (bf16*) (ws + 85458944);      // 67108864  (B*H,S,512)
  bf16*  qnopeb= (bf16*) (ws + 85458944);      // 16777216  alias in outl (dead pre-attn)
  bf16*  qpeb  = (bf16*) (ws + 102236160);     //  8388608  alias
  bf16*  kbT   = (bf16*) (ws + 110624768);     //  2097152  alias
  bf16*  hb    = (bf16*) (ws + 112721920);     // 16777216  alias
  bf16*  qnb   = (bf16*) (ws + 129499136);     //  8388608  alias
  bf16*  qpw   = (bf16*) (ws + 137887744);     //  4194304  alias
  bf16*  kvab  = (bf16*) (ws + 142082048);     //  2359296  alias (ends 144441344)
  bf16*  voutb = (bf16*) (ws + 152567808);     // 16777216  (B,S,2048)
  bf16*  Kd    = (bf16*) (ws + 169345024);     //  4194304  (B,512,S) ends 173539328

  static_assert(sizeof(v8bf) == 16, "v8bf must be 16B");
  hipFuncSetAttribute((const void*)attn_mfma_kernel,
                      hipFuncAttributeMaxDynamicSharedMemorySize, SMEM_BYTES);

  cossin_kernel<<<256, 256, 0, stream>>>(pos, cosT, sinT);

  // fused pre-casts to bf16 (hidden, qn_w, qpe_w, kva_w)
  cast4_kernel<<<7744, 256, 0, stream>>>(hidden, hb, qn_w, qnb, qpe_w, qpw, kva_w, kvab);

  // fused projections: q_nope, q_pe, ckv  (A = hb, K=2048)
  proj3_kernel<<<dim3(29,32,1),256,0,stream>>>(hb, qnb, qpw, kvab,
                                               qnopeb, qpeb, ckvb);

  kbT_kernel<<<dim3(8,2,16), 256, 0, stream>>>(kb_w, kbT);
  build_k_kernel<<<4096, 256, 0, stream>>>(ckvb, ln_w, cosT, sinT, Kb);
  castf2b_kernel<<<512, 256, 0, stream>>>(vb_w, vbb, 131072);   // into dead ckvb
  tposeV_kernel<<<dim3(8,32,2), 256, 0, stream>>>(Kb, Kd);
  rope_q_kernel<<<8192, 256, 0, stream>>>(qpeb, cosT, sinT, Qb);

  // q_lat = q_nope @ kbT[n]^T  (per (b,n): 2048x512, K=128), *SCALE -> Q[:, :512]
  gemm2_kernel<bf16><<<dim3(4,16,32),256,0,stream>>>(
      qnopeb,2048, 16,(long)S_*2048,128,  kbT,128, 16,0,65536,
      Qb,576, 1,(long)S_*576,0,  512,128, SCALE_F);

  attn_mfma_kernel<<<dim3(512), 512, SMEM_BYTES, stream>>>(Qb, Kb, Kd, outl);

  castf2b_kernel<<<2048, 256, 0, stream>>>(o_w, ob, 524288);    // into dead Qb

  // v_out = out_lat @ vbb[n]^T  (per (b,n): 2048x128, K=512) -> (B,S,H*DV)
  gemm2_kernel<bf16><<<dim3(1,16,32),256,0,stream>>>(
      outl,512, 1,(long)S_*512,0,  vbb,512, 16,0,65536,
      voutb,2048, 16,(long)S_*2048,128,  128,512, 1.f);

  // out = v_out @ ob^T  (4096 x 2048)
  gemm2_kernel<float><<<dim3(16,32,1),256,0,stream>>>(
      voutb,2048, 1,0,0,  ob,2048, 1,0,0,  out,2048, 1,0,0,  2048,2048, 1.f);
}